// Round 4
// baseline (1289.786 us; speedup 1.0000x reference)
//
#include <hip/hip_runtime.h>

#define T_STEPS 8192
#define DIN     2048
#define DH      2048
#define DTOT    4096
#define QG      8
#define NQQ     32

#define INV4PI  0.0795774715459476678f
#define TWOPI   6.28318530717958648f

#if __has_builtin(__builtin_amdgcn_cosf)
#define COS_REV(x) __builtin_amdgcn_cosf(x)          // cos(2*pi*x)
#else
#define COS_REV(x) __cosf((x) * TWOPI)
#endif
#if __has_builtin(__builtin_amdgcn_sinf)
#define SIN_REV(x) __builtin_amdgcn_sinf(x)          // sin(2*pi*x)
#else
#define SIN_REV(x) __sinf((x) * TWOPI)
#endif
#if __has_builtin(__builtin_amdgcn_rcpf)
#define RCPF(x) __builtin_amdgcn_rcpf(x)
#else
#define RCPF(x) (1.0f / (x))
#endif

// x * dpp(x): used only with ctrls whose 4-member product is direction-safe
#define DPP_MUL(x, ctrl)                                                        \
  ((x) * __int_as_float(__builtin_amdgcn_update_dpp(                            \
             __float_as_int(x), __float_as_int(x), (ctrl), 0xF, 0xF, false)))
// dpp move (quad_perm broadcast)
#define DPP_MOV(x, ctrl)                                                        \
  __int_as_float(__builtin_amdgcn_update_dpp(                                   \
      __float_as_int(x), __float_as_int(x), (ctrl), 0xF, 0xF, false))

// ---------------------------------------------------------------------------
// Kernel 1: for 4 timesteps per block, all 32 (gate,q) angles:
//   a = (x_t . W[q,:DIN] + b[q]) * INV4PI  (half-angle in revolutions)
// writes Af[t][m] = float4(cos a(2m), sin a(2m), cos a(2m+1), sin a(2m+1)),
// m = 4*gate + q/2.
// ---------------------------------------------------------------------------
__global__ __launch_bounds__(256) void gemm_kernel(
    const float* __restrict__ x,
    const float* __restrict__ Wf, const float* __restrict__ Wi,
    const float* __restrict__ Wu, const float* __restrict__ Wo,
    const float* __restrict__ bf, const float* __restrict__ bi,
    const float* __restrict__ bu, const float* __restrict__ bo,
    float* __restrict__ Af) {
  __shared__ float4 xs[2048];                // 4 rows x 512 float4 = 32 KB
  const int t0  = blockIdx.x * 4;
  const int tid = threadIdx.x;

  const float4* xrow = (const float4*)(x + (size_t)t0 * DIN);
#pragma unroll
  for (int kk = 0; kk < 8; ++kk) xs[tid + 256 * kk] = xrow[tid + 256 * kk];
  __syncthreads();

  const int wave = tid >> 6;
  const int lane = tid & 63;
  const float* W  = (wave == 0) ? Wf : (wave == 1) ? Wi : (wave == 2) ? Wu : Wo;
  const float* bg = (wave == 0) ? bf : (wave == 1) ? bi : (wave == 2) ? bu : bo;

  for (int q = 0; q < QG; ++q) {
    const float4* wrow = (const float4*)(W + (size_t)q * DTOT);
    float ac0 = 0.f, ac1 = 0.f, ac2 = 0.f, ac3 = 0.f;
#pragma unroll
    for (int jj = 0; jj < 8; ++jj) {
      const float4 w4 = wrow[lane + 64 * jj];
      const float4 x0 = xs[lane + 64 * jj];
      const float4 x1 = xs[512 + lane + 64 * jj];
      const float4 x2 = xs[1024 + lane + 64 * jj];
      const float4 x3 = xs[1536 + lane + 64 * jj];
      ac0 = fmaf(w4.x, x0.x, ac0); ac0 = fmaf(w4.y, x0.y, ac0);
      ac0 = fmaf(w4.z, x0.z, ac0); ac0 = fmaf(w4.w, x0.w, ac0);
      ac1 = fmaf(w4.x, x1.x, ac1); ac1 = fmaf(w4.y, x1.y, ac1);
      ac1 = fmaf(w4.z, x1.z, ac1); ac1 = fmaf(w4.w, x1.w, ac1);
      ac2 = fmaf(w4.x, x2.x, ac2); ac2 = fmaf(w4.y, x2.y, ac2);
      ac2 = fmaf(w4.z, x2.z, ac2); ac2 = fmaf(w4.w, x2.w, ac2);
      ac3 = fmaf(w4.x, x3.x, ac3); ac3 = fmaf(w4.y, x3.y, ac3);
      ac3 = fmaf(w4.z, x3.z, ac3); ac3 = fmaf(w4.w, x3.w, ac3);
    }
#pragma unroll
    for (int off = 32; off > 0; off >>= 1) {
      ac0 += __shfl_xor(ac0, off); ac1 += __shfl_xor(ac1, off);
      ac2 += __shfl_xor(ac2, off); ac3 += __shfl_xor(ac3, off);
    }
    if (lane == 0) {
      const float bq = bg[q];
      const int   mb = 4 * wave + (q >> 1);
      const int   cp = (q & 1) * 2;
      const float av[4] = {ac0, ac1, ac2, ac3};
#pragma unroll
      for (int k = 0; k < 4; ++k) {
        const float a = (av[k] + bq) * INV4PI;
        const size_t base = (((size_t)(t0 + k) * 16 + mb) << 2) + cp;
        Af[base]     = COS_REV(a);
        Af[base + 1] = SIN_REV(a);
      }
    }
  }
}

// ---------------------------------------------------------------------------
// Kernel 2: S[qq] = sum_d W_gate[q, DIN+d] * INV4PI
// ---------------------------------------------------------------------------
__global__ __launch_bounds__(64) void rowsum_kernel(
    const float* __restrict__ Wf, const float* __restrict__ Wi,
    const float* __restrict__ Wu, const float* __restrict__ Wo,
    float* __restrict__ S) {
  const int b    = blockIdx.x;
  const int gate = b >> 3;
  const int q    = b & 7;
  const int lane = threadIdx.x;
  const float* W = (gate == 0) ? Wf : (gate == 1) ? Wi : (gate == 2) ? Wu : Wo;
  const float4* row = (const float4*)(W + (size_t)q * DTOT + DIN);
  float acc = 0.f;
#pragma unroll
  for (int j = 0; j < 8; ++j) {
    float4 w4 = row[lane + 64 * j];
    acc += w4.x + w4.y + w4.z + w4.w;
  }
#pragma unroll
  for (int off = 32; off > 0; off >>= 1) acc += __shfl_xor(acc, off);
  if (lane == 0) S[b] = acc * INV4PI;
}

// ---------------------------------------------------------------------------
// Kernel 3: serial scan, one wave. Lane li=lane&15: gate g=li&3, pair j=li>>2,
// owns angles qq = 8g+2j, 8g+2j+1 (Af pair index m = 4g+j).
// cos(th) = cosA*cos(kh) - sinA*sin(kh), k = 2*pi*S: the lane's pair-product
// collapses to pc = a0+a1*u+a2*u^2 + h*(b0+b1*u), u=h^2 (coefs off-chain).
// Product over the gate's 4 pairs via DPP row_ror:4 + row_ror:8 (direction-
// safe: full 4-member product either way). Gates land interleaved mod 4 ->
// every quad holds [f,i,g,o]; quad_perm broadcasts (pure VGPR, no readlane).
// Gate nonlinearity: deg-9 odd polys (sigma Taylor; tanh economized Taylor).
// tanh(c): Pade[5/4] + single v_rcp (the only transcendental on the chain).
// ---------------------------------------------------------------------------
__global__ __launch_bounds__(64) void scan_kernel(
    const float4* __restrict__ A4, const float* __restrict__ S,
    float* __restrict__ hbuf, float* __restrict__ cfin) {
  const int lane = threadIdx.x;
  const int li = lane & 15;
  const int g  = li & 3;
  const int j  = li >> 2;
  const int m  = 4 * g + j;

  const float k1 = S[8 * g + 2 * j]     * TWOPI;
  const float k2 = S[8 * g + 2 * j + 1] * TWOPI;
  const float k1s = k1 * k1, k2s = k2 * k2;
  const float K2h  = 0.5f * (k1s + k2s);
  const float P12  = k1 * k2;
  const float C4   = (k1s * k1s + k2s * k2s) * (1.f / 24.f) + 0.25f * k1s * k2s;
  const float K26  = (k1s + k2s) * (1.f / 6.f);
  const float c12a = 0.5f * k1s + (1.f / 6.f) * k2s;
  const float c12b = 0.5f * k2s + (1.f / 6.f) * k1s;

  const bool isT = (g == 2);   // update gate -> tanh; others sigmoid
  const float d0 = isT ? 0.f          : 0.5f;
  const float d1 = isT ? 0.9999864f   : 0.25f;
  const float d3 = isT ? -0.3329971f  : -1.f / 48.f;
  const float d5 = isT ? 0.1309016f   : 1.f / 480.f;
  const float d7 = isT ? -0.0463194f  : -17.f / 80640.f;
  const float d9 = isT ? 0.0100394f   : 31.f / 1451520.f;

  float c = 0.f, h = 0.f;

  float4 buf[8];
#pragma unroll
  for (int p = 0; p < 8; ++p) buf[p] = A4[(size_t)p * 16 + m];

  for (int t0 = 0; t0 < T_STEPS; t0 += 8) {
#pragma unroll
    for (int p = 0; p < 8; ++p) {
      const float4 D = buf[p];
      int tp = t0 + p + 8;
      if (tp > T_STEPS - 1) tp = T_STEPS - 1;
      buf[p] = A4[(size_t)tp * 16 + m];          // 8-deep register prefetch

      // ---- off-chain per-step coefficients (independent of h) ----
      const float cc = D.x * D.z, ss = D.y * D.w;
      const float cs = D.x * D.w, sc = D.y * D.z;
      const float sp   = ss * P12;
      const float a0   = cc;
      const float a1   = fmaf(-K2h, cc, sp);
      const float a2   = fmaf(C4, cc, -(sp * K26));
      const float csk2 = cs * k2, sck1 = sc * k1;
      const float b0   = -(csk2 + sck1);
      const float b1   = fmaf(csk2, c12a, sck1 * c12b);

      // ---- chain ----
      const float u  = h * h;
      const float w3 = fmaf(b1, u, b0);
      const float w1 = fmaf(a2, u, a1);
      const float w2 = fmaf(w1, u, a0);
      float pc = fmaf(h, w3, w2);                // cos(th1)*cos(th2)

      pc = DPP_MUL(pc, 0x124);                   // row_ror:4
      pc = DPP_MUL(pc, 0x128);                   // row_ror:8 -> Q = prod 8 cos

      const float tQ = pc * pc;                  // Q^2 = P
      const float xg = fmaf(2.f, tQ, -1.f);      // 2P-1
      const float u2 = xg * xg;
      float w = fmaf(d9, u2, d7);
      w = fmaf(w, u2, d5);
      w = fmaf(w, u2, d3);
      w = fmaf(w, u2, d1);
      const float gv = fmaf(xg, w, d0);          // gate value (per-lane act.)

      const float f_b = DPP_MOV(gv, 0x00);       // quad lane0 = forget
      const float i_b = DPP_MOV(gv, 0x55);       // input
      const float g_b = DPP_MOV(gv, 0xAA);       // update
      const float o_b = DPP_MOV(gv, 0xFF);       // output

      c = fmaf(f_b, c, i_b * g_b);
      // tanh(c), Pade[5/4]: c*(945+105u+u^2)/(945+420u+15u^2)
      const float u3 = c * c;
      const float nn = u3 + 105.f;
      const float Pn = fmaf(u3, nn, 945.f);
      const float q2 = fmaf(15.f, u3, 420.f);
      const float Qd = fmaf(u3, q2, 945.f);
      const float rc = RCPF(Qd);
      const float th = (c * Pn) * rc;
      h = o_b * th;

      if (lane == 0) hbuf[t0 + p] = h;
    }
  }
  if (lane == 0) cfin[0] = c;
}

// ---------------------------------------------------------------------------
// Kernel 4: broadcast h_t over DH, plus hx / cx tails.
// ---------------------------------------------------------------------------
__global__ __launch_bounds__(256) void bcast_kernel(
    const float* __restrict__ hbuf, const float* __restrict__ cfin,
    float* __restrict__ out) {
  const int b = blockIdx.x;
  float v;
  size_t off;
  if (b < T_STEPS) {
    v = hbuf[b];
    off = (size_t)b * DH;
  } else if (b == T_STEPS) {
    v = hbuf[T_STEPS - 1];
    off = (size_t)T_STEPS * DH;
  } else {
    v = cfin[0];
    off = (size_t)T_STEPS * DH + DH;
  }
  const float4 v4 = make_float4(v, v, v, v);
  float4* dst = (float4*)(out + off);
  dst[threadIdx.x]       = v4;
  dst[threadIdx.x + 256] = v4;
}

extern "C" void kernel_launch(void* const* d_in, const int* in_sizes, int n_in,
                              void* d_out, int out_size, void* d_ws, size_t ws_size,
                              hipStream_t stream) {
  const float* x  = (const float*)d_in[0];
  const float* Wf = (const float*)d_in[1];
  const float* bf = (const float*)d_in[2];
  const float* Wi = (const float*)d_in[3];
  const float* bi = (const float*)d_in[4];
  const float* Wu = (const float*)d_in[5];
  const float* bu = (const float*)d_in[6];
  const float* Wo = (const float*)d_in[7];
  const float* bo = (const float*)d_in[8];
  float* out = (float*)d_out;

  // ws layout (floats): Af[8192*16*4] | S[32] | hbuf[8192] | cfin[1]
  float* Af   = (float*)d_ws;
  float* S    = Af + (size_t)T_STEPS * 64;
  float* hbuf = S + NQQ;
  float* cfin = hbuf + T_STEPS;

  hipLaunchKernelGGL(gemm_kernel, dim3(T_STEPS / 4), dim3(256), 0, stream,
                     x, Wf, Wi, Wu, Wo, bf, bi, bu, bo, Af);
  hipLaunchKernelGGL(rowsum_kernel, dim3(NQQ), dim3(64), 0, stream,
                     Wf, Wi, Wu, Wo, S);
  hipLaunchKernelGGL(scan_kernel, dim3(1), dim3(64), 0, stream,
                     (const float4*)Af, S, hbuf, cfin);
  hipLaunchKernelGGL(bcast_kernel, dim3(T_STEPS + 2), dim3(256), 0, stream,
                     hbuf, cfin, out);
}

// Round 5
// 298.425 us; speedup vs baseline: 4.3220x; 4.3220x over previous
//
#include <hip/hip_runtime.h>

#define T_STEPS 8192
#define DIN     2048
#define DH      2048
#define DTOT    4096
#define QG      8
#define NQQ     32

#define GT      8      // timesteps per gemm block
#define CH      64     // output steps per scan block
#define WU      192    // warmup steps (contraction >= 0.73/step => ~1e-8 error)
#define NB      (T_STEPS / CH)

#define INV4PI  0.0795774715459476678f
#define TWOPI   6.28318530717958648f

#if __has_builtin(__builtin_amdgcn_cosf)
#define COS_REV(x) __builtin_amdgcn_cosf(x)          // cos(2*pi*x)
#else
#define COS_REV(x) __cosf((x) * TWOPI)
#endif
#if __has_builtin(__builtin_amdgcn_sinf)
#define SIN_REV(x) __builtin_amdgcn_sinf(x)          // sin(2*pi*x)
#else
#define SIN_REV(x) __sinf((x) * TWOPI)
#endif
#if __has_builtin(__builtin_amdgcn_rcpf)
#define RCPF(x) __builtin_amdgcn_rcpf(x)
#else
#define RCPF(x) (1.0f / (x))
#endif

#define DPP_MUL(x, ctrl)                                                        \
  ((x) * __int_as_float(__builtin_amdgcn_update_dpp(                            \
             __float_as_int(x), __float_as_int(x), (ctrl), 0xF, 0xF, false)))
#define DPP_MOV(x, ctrl)                                                        \
  __int_as_float(__builtin_amdgcn_update_dpp(                                   \
      __float_as_int(x), __float_as_int(x), (ctrl), 0xF, 0xF, false))

// ---------------------------------------------------------------------------
// Kernel 1: 8 timesteps per block; all 32 (gate,q) half-angles per step.
// Emits Af[t][m] = float4(cos a(2m), sin a(2m), cos a(2m+1), sin a(2m+1)),
// m = 4*gate + q/2, a = (x_t . W[q,:DIN] + b[q]) / (4*pi) (revolutions).
// ---------------------------------------------------------------------------
__global__ __launch_bounds__(256) void gemm_kernel(
    const float* __restrict__ x,
    const float* __restrict__ Wf, const float* __restrict__ Wi,
    const float* __restrict__ Wu, const float* __restrict__ Wo,
    const float* __restrict__ bf, const float* __restrict__ bi,
    const float* __restrict__ bu, const float* __restrict__ bo,
    float* __restrict__ Af) {
  __shared__ float4 xs[GT * 512];            // 8 rows x 512 float4 = 64 KB
  const int t0  = blockIdx.x * GT;
  const int tid = threadIdx.x;

  const float4* xrow = (const float4*)(x + (size_t)t0 * DIN);
#pragma unroll
  for (int kk = 0; kk < 2 * GT; ++kk) xs[tid + 256 * kk] = xrow[tid + 256 * kk];
  __syncthreads();

  const int wave = tid >> 6;
  const int lane = tid & 63;
  const float* W  = (wave == 0) ? Wf : (wave == 1) ? Wi : (wave == 2) ? Wu : Wo;
  const float* bg = (wave == 0) ? bf : (wave == 1) ? bi : (wave == 2) ? bu : bo;

  for (int q = 0; q < QG; ++q) {
    const float4* wrow = (const float4*)(W + (size_t)q * DTOT);
    float ac[GT];
#pragma unroll
    for (int k = 0; k < GT; ++k) ac[k] = 0.f;
#pragma unroll
    for (int jj = 0; jj < 8; ++jj) {
      const float4 w4 = wrow[lane + 64 * jj];
#pragma unroll
      for (int k = 0; k < GT; ++k) {
        const float4 xv = xs[512 * k + lane + 64 * jj];
        ac[k] = fmaf(w4.x, xv.x, ac[k]);
        ac[k] = fmaf(w4.y, xv.y, ac[k]);
        ac[k] = fmaf(w4.z, xv.z, ac[k]);
        ac[k] = fmaf(w4.w, xv.w, ac[k]);
      }
    }
#pragma unroll
    for (int off = 32; off > 0; off >>= 1) {
#pragma unroll
      for (int k = 0; k < GT; ++k) ac[k] += __shfl_xor(ac[k], off);
    }
    if (lane == 0) {
      const float bq = bg[q];
      const int   mb = 4 * wave + (q >> 1);
      const int   cp = (q & 1) * 2;
#pragma unroll
      for (int k = 0; k < GT; ++k) {
        const float a = (ac[k] + bq) * INV4PI;
        const size_t base = (((size_t)(t0 + k) * 16 + mb) << 2) + cp;
        Af[base]     = COS_REV(a);
        Af[base + 1] = SIN_REV(a);
      }
    }
  }
}

// ---------------------------------------------------------------------------
// Kernel 2: S[qq] = sum_d W_gate[q, DIN+d] * INV4PI
// ---------------------------------------------------------------------------
__global__ __launch_bounds__(64) void rowsum_kernel(
    const float* __restrict__ Wf, const float* __restrict__ Wi,
    const float* __restrict__ Wu, const float* __restrict__ Wo,
    float* __restrict__ S) {
  const int b    = blockIdx.x;
  const int gate = b >> 3;
  const int q    = b & 7;
  const int lane = threadIdx.x;
  const float* W = (gate == 0) ? Wf : (gate == 1) ? Wi : (gate == 2) ? Wu : Wo;
  const float4* row = (const float4*)(W + (size_t)q * DTOT + DIN);
  float acc = 0.f;
#pragma unroll
  for (int j = 0; j < 8; ++j) {
    float4 w4 = row[lane + 64 * j];
    acc += w4.x + w4.y + w4.z + w4.w;
  }
#pragma unroll
  for (int off = 32; off > 0; off >>= 1) acc += __shfl_xor(acc, off);
  if (lane == 0) S[b] = acc * INV4PI;
}

// ---------------------------------------------------------------------------
// Kernel 3: chunk-parallel scan. Block b outputs t in [b*CH, b*CH+CH), after
// warming up from t = max(0, b*CH - WU) with state (c,h)=(0,0): the LSTM cell
// contracts (f <= sigma(1) = 0.731), so the warmup trajectory converges to
// the true one to ~1e-8 before any output is written. Warmup does no stores;
// output h is batched into float4 (one store per 4 steps, rotation gap >
// store latency) so no per-step vmcnt drain sits on the chain.
// Per-step math identical to the R4-verified body.
// ---------------------------------------------------------------------------
__global__ __launch_bounds__(64) void scan_kernel(
    const float4* __restrict__ A4, const float* __restrict__ S,
    float* __restrict__ hbuf, float* __restrict__ cfin) {
  const int blk  = blockIdx.x;
  const int lane = threadIdx.x;
  const int li = lane & 15;
  const int g  = li & 3;
  const int j  = li >> 2;
  const int m  = 4 * g + j;

  const int tout0  = blk * CH;
  int tstart = tout0 - WU;
  if (tstart < 0) tstart = 0;
  const int warm_groups = (tout0 - tstart) >> 3;

  const float k1 = S[8 * g + 2 * j]     * TWOPI;
  const float k2 = S[8 * g + 2 * j + 1] * TWOPI;
  const float k1s = k1 * k1, k2s = k2 * k2;
  const float K2h  = 0.5f * (k1s + k2s);
  const float P12  = k1 * k2;
  const float C4   = (k1s * k1s + k2s * k2s) * (1.f / 24.f) + 0.25f * k1s * k2s;
  const float K26  = (k1s + k2s) * (1.f / 6.f);
  const float c12a = 0.5f * k1s + (1.f / 6.f) * k2s;
  const float c12b = 0.5f * k2s + (1.f / 6.f) * k1s;

  const bool isT = (g == 2);   // update gate -> tanh; others sigmoid
  const float d0 = isT ? 0.f          : 0.5f;
  const float d1 = isT ? 0.9999864f   : 0.25f;
  const float d3 = isT ? -0.3329971f  : -1.f / 48.f;
  const float d5 = isT ? 0.1309016f   : 1.f / 480.f;
  const float d7 = isT ? -0.0463194f  : -17.f / 80640.f;
  const float d9 = isT ? 0.0100394f   : 31.f / 1451520.f;

  float c = 0.f, h = 0.f;

  float4 buf[8];
#pragma unroll
  for (int p = 0; p < 8; ++p) buf[p] = A4[(size_t)(tstart + p) * 16 + m];

  // one step; p must be an unroll-time constant so buf[] stays in registers
  auto step = [&](int p, int t) {
    const float4 D = buf[p];
    int tp = t + 8;
    if (tp > T_STEPS - 1) tp = T_STEPS - 1;
    buf[p] = A4[(size_t)tp * 16 + m];          // 8-deep register prefetch

    const float cc = D.x * D.z, ss = D.y * D.w;
    const float cs = D.x * D.w, sc = D.y * D.z;
    const float sp   = ss * P12;
    const float a0   = cc;
    const float a1   = fmaf(-K2h, cc, sp);
    const float a2   = fmaf(C4, cc, -(sp * K26));
    const float csk2 = cs * k2, sck1 = sc * k1;
    const float b0   = -(csk2 + sck1);
    const float b1   = fmaf(csk2, c12a, sck1 * c12b);

    const float u  = h * h;
    const float w3 = fmaf(b1, u, b0);
    const float w1 = fmaf(a2, u, a1);
    const float w2 = fmaf(w1, u, a0);
    float pc = fmaf(h, w3, w2);                // cos(th1)*cos(th2)

    pc = DPP_MUL(pc, 0x124);                   // row_ror:4
    pc = DPP_MUL(pc, 0x128);                   // row_ror:8 -> prod of 8 cos

    const float tQ = pc * pc;                  // P
    const float xg = fmaf(2.f, tQ, -1.f);      // 2P-1
    const float u2 = xg * xg;
    float wp = fmaf(d9, u2, d7);
    wp = fmaf(wp, u2, d5);
    wp = fmaf(wp, u2, d3);
    wp = fmaf(wp, u2, d1);
    const float gv = fmaf(xg, wp, d0);

    const float f_b = DPP_MOV(gv, 0x00);
    const float i_b = DPP_MOV(gv, 0x55);
    const float g_b = DPP_MOV(gv, 0xAA);
    const float o_b = DPP_MOV(gv, 0xFF);

    c = fmaf(f_b, c, i_b * g_b);
    const float u3 = c * c;                    // tanh(c): Pade[5/4]
    const float nn = u3 + 105.f;
    const float Pn = fmaf(u3, nn, 945.f);
    const float q2 = fmaf(15.f, u3, 420.f);
    const float Qd = fmaf(u3, q2, 945.f);
    const float rc = RCPF(Qd);
    const float th = (c * Pn) * rc;
    h = o_b * th;
  };

  // ---- warmup: no stores ----
  for (int gI = 0; gI < warm_groups; ++gI) {
    const int tb = tstart + gI * 8;
#pragma unroll
    for (int p = 0; p < 8; ++p) step(p, tb + p);
  }

  // ---- output: CH steps, h batched 4-wide ----
  float4* Hout = (float4*)(hbuf + tout0);
  float4 hacc;
  for (int gI = 0; gI < CH / 8; ++gI) {
    const int tb = tout0 + gI * 8;
#pragma unroll
    for (int p = 0; p < 8; ++p) {
      step(p, tb + p);
      if ((p & 3) == 0)      hacc.x = h;
      else if ((p & 3) == 1) hacc.y = h;
      else if ((p & 3) == 2) hacc.z = h;
      else {
        hacc.w = h;
        if (lane == 0) Hout[(gI * 8 + p - 3) >> 2] = hacc;
      }
    }
  }
  if (blk == NB - 1 && lane == 0) cfin[0] = c;
}

// ---------------------------------------------------------------------------
// Kernel 4: broadcast h_t over DH, plus hx / cx tails.
// ---------------------------------------------------------------------------
__global__ __launch_bounds__(256) void bcast_kernel(
    const float* __restrict__ hbuf, const float* __restrict__ cfin,
    float* __restrict__ out) {
  const int b = blockIdx.x;
  float v;
  size_t off;
  if (b < T_STEPS) {
    v = hbuf[b];
    off = (size_t)b * DH;
  } else if (b == T_STEPS) {
    v = hbuf[T_STEPS - 1];
    off = (size_t)T_STEPS * DH;
  } else {
    v = cfin[0];
    off = (size_t)T_STEPS * DH + DH;
  }
  const float4 v4 = make_float4(v, v, v, v);
  float4* dst = (float4*)(out + off);
  dst[threadIdx.x]       = v4;
  dst[threadIdx.x + 256] = v4;
}

extern "C" void kernel_launch(void* const* d_in, const int* in_sizes, int n_in,
                              void* d_out, int out_size, void* d_ws, size_t ws_size,
                              hipStream_t stream) {
  const float* x  = (const float*)d_in[0];
  const float* Wf = (const float*)d_in[1];
  const float* bf = (const float*)d_in[2];
  const float* Wi = (const float*)d_in[3];
  const float* bi = (const float*)d_in[4];
  const float* Wu = (const float*)d_in[5];
  const float* bu = (const float*)d_in[6];
  const float* Wo = (const float*)d_in[7];
  const float* bo = (const float*)d_in[8];
  float* out = (float*)d_out;

  // ws layout (floats): Af[8192*16*4] | S[32] | hbuf[8192] | cfin[1]
  float* Af   = (float*)d_ws;
  float* S    = Af + (size_t)T_STEPS * 64;
  float* hbuf = S + NQQ;
  float* cfin = hbuf + T_STEPS;

  hipLaunchKernelGGL(gemm_kernel, dim3(T_STEPS / GT), dim3(256), 0, stream,
                     x, Wf, Wi, Wu, Wo, bf, bi, bu, bo, Af);
  hipLaunchKernelGGL(rowsum_kernel, dim3(NQQ), dim3(64), 0, stream,
                     Wf, Wi, Wu, Wo, S);
  hipLaunchKernelGGL(scan_kernel, dim3(NB), dim3(64), 0, stream,
                     (const float4*)Af, S, hbuf, cfin);
  hipLaunchKernelGGL(bcast_kernel, dim3(T_STEPS + 2), dim3(256), 0, stream,
                     hbuf, cfin, out);
}

// Round 6
// 195.071 us; speedup vs baseline: 6.6119x; 1.5298x over previous
//
#include <hip/hip_runtime.h>

#define T_STEPS 8192
#define DIN     2048
#define DH      2048
#define DTOT    4096
#define QG      8
#define NQQ     32

#define CH      64     // output steps per scan block
#define WU      96     // warmup steps (contraction <=0.73/step; 0.85^96 ~ 6e-7)
#define NB      (T_STEPS / CH)
#define KSTEPS  (DIN / 32)   // 64 MFMA K-steps

#define INV4PI  0.0795774715459476678f
#define TWOPI   6.28318530717958648f

#if __has_builtin(__builtin_amdgcn_cosf)
#define COS_REV(x) __builtin_amdgcn_cosf(x)          // cos(2*pi*x)
#else
#define COS_REV(x) __cosf((x) * TWOPI)
#endif
#if __has_builtin(__builtin_amdgcn_sinf)
#define SIN_REV(x) __builtin_amdgcn_sinf(x)          // sin(2*pi*x)
#else
#define SIN_REV(x) __sinf((x) * TWOPI)
#endif
#if __has_builtin(__builtin_amdgcn_rcpf)
#define RCPF(x) __builtin_amdgcn_rcpf(x)
#else
#define RCPF(x) (1.0f / (x))
#endif

#define DPP_MUL(x, ctrl)                                                        \
  ((x) * __int_as_float(__builtin_amdgcn_update_dpp(                            \
             __float_as_int(x), __float_as_int(x), (ctrl), 0xF, 0xF, false)))
#define DPP_MOV(x, ctrl)                                                        \
  __int_as_float(__builtin_amdgcn_update_dpp(                                   \
      __float_as_int(x), __float_as_int(x), (ctrl), 0xF, 0xF, false))

typedef short bf16x8 __attribute__((ext_vector_type(8)));
typedef float f32x4  __attribute__((ext_vector_type(4)));
typedef int   i32x4  __attribute__((ext_vector_type(4)));
union Pack8 { i32x4 i; bf16x8 b; };

__device__ __forceinline__ unsigned short f2bf_rne(float f) {
  unsigned u = __float_as_uint(f);
  return (unsigned short)((u + 0x7FFFu + ((u >> 16) & 1u)) >> 16);
}

// ---------------------------------------------------------------------------
// Kernel 0 (prep): pack W gate rows (input part, k<2048) into MFMA B-operand
// fragments, hi/lo bf16 split (RNE). Block blk = kk*2+nt (kk=K-step, nt=N-
// tile); lane: n=lane&15 -> qq=nt*16+n (qq = 8*gate+q), k = kk*32+quad*8+j.
// Entry (blk,lane) = 8 consecutive bf16 = 16B; gemm loads it as bf16x8.
// ---------------------------------------------------------------------------
__global__ __launch_bounds__(64) void prep_kernel(
    const float* __restrict__ Wf, const float* __restrict__ Wi,
    const float* __restrict__ Wu, const float* __restrict__ Wo,
    unsigned short* __restrict__ BhiS, unsigned short* __restrict__ BloS) {
  const int blk  = blockIdx.x;
  const int kk   = blk >> 1;
  const int nt   = blk & 1;
  const int lane = threadIdx.x;
  const int n    = lane & 15;
  const int quad = lane >> 4;
  const int qq   = nt * 16 + n;
  const int gate = qq >> 3;
  const int q    = qq & 7;
  const float* W = (gate == 0) ? Wf : (gate == 1) ? Wi : (gate == 2) ? Wu : Wo;
  const float* src = W + (size_t)q * DTOT + kk * 32 + quad * 8;
  const size_t base = ((size_t)blk * 64 + lane) * 8;
#pragma unroll
  for (int j = 0; j < 8; ++j) {
    const float w = src[j];
    const unsigned short h = f2bf_rne(w);
    const float hf = __uint_as_float(((unsigned)h) << 16);
    const unsigned short l = f2bf_rne(w - hf);
    BhiS[base + j] = h;
    BloS[base + j] = l;
  }
}

// ---------------------------------------------------------------------------
// Kernel 1 (MFMA gemm): one wave per 16(M)x32(N) C-tile, 512 blocks.
// A = X[t0..t0+15][:2048] fp32, split hi/lo bf16 on the fly (truncation split:
// lo catches the tail, combined error ~2^-16). B from prep. 3 MFMAs per
// (k-step, n-tile): hh + hl + lh. Epilogue: angle=(acc+b)*INV4PI, emit
// Af[t][float offset 2*qq] = {cos, sin} (same layout the scan consumes).
// ---------------------------------------------------------------------------
__global__ __launch_bounds__(64) void mfma_gemm_kernel(
    const float* __restrict__ x,
    const bf16x8* __restrict__ Bhi, const bf16x8* __restrict__ Blo,
    const float* __restrict__ bcat,
    float* __restrict__ Af) {
  const int lane = threadIdx.x & 63;
  const int t0   = blockIdx.x * 16;
  const int n    = lane & 15;       // A: m-index loader; C: n-index
  const int quad = lane >> 4;
  const float* xrow = x + (size_t)(t0 + n) * DIN + quad * 8;

  f32x4 acc0 = {0.f, 0.f, 0.f, 0.f};
  f32x4 acc1 = {0.f, 0.f, 0.f, 0.f};

#pragma unroll 2
  for (int kk = 0; kk < KSTEPS; ++kk) {
    const float4* p = (const float4*)(xrow + kk * 32);
    const float4 a0 = p[0];
    const float4 a1 = p[1];

    // truncation hi/lo split + pack (pairs in k order)
    Pack8 ah, al;
    {
      const unsigned u0 = __float_as_uint(a0.x), u1 = __float_as_uint(a0.y);
      const unsigned u2 = __float_as_uint(a0.z), u3 = __float_as_uint(a0.w);
      const unsigned u4 = __float_as_uint(a1.x), u5 = __float_as_uint(a1.y);
      const unsigned u6 = __float_as_uint(a1.z), u7 = __float_as_uint(a1.w);
      ah.i[0] = (int)((u0 >> 16) | (u1 & 0xFFFF0000u));
      ah.i[1] = (int)((u2 >> 16) | (u3 & 0xFFFF0000u));
      ah.i[2] = (int)((u4 >> 16) | (u5 & 0xFFFF0000u));
      ah.i[3] = (int)((u6 >> 16) | (u7 & 0xFFFF0000u));
      const float l0 = a0.x - __uint_as_float(u0 & 0xFFFF0000u);
      const float l1 = a0.y - __uint_as_float(u1 & 0xFFFF0000u);
      const float l2 = a0.z - __uint_as_float(u2 & 0xFFFF0000u);
      const float l3 = a0.w - __uint_as_float(u3 & 0xFFFF0000u);
      const float l4 = a1.x - __uint_as_float(u4 & 0xFFFF0000u);
      const float l5 = a1.y - __uint_as_float(u5 & 0xFFFF0000u);
      const float l6 = a1.z - __uint_as_float(u6 & 0xFFFF0000u);
      const float l7 = a1.w - __uint_as_float(u7 & 0xFFFF0000u);
      al.i[0] = (int)((__float_as_uint(l0) >> 16) | (__float_as_uint(l1) & 0xFFFF0000u));
      al.i[1] = (int)((__float_as_uint(l2) >> 16) | (__float_as_uint(l3) & 0xFFFF0000u));
      al.i[2] = (int)((__float_as_uint(l4) >> 16) | (__float_as_uint(l5) & 0xFFFF0000u));
      al.i[3] = (int)((__float_as_uint(l6) >> 16) | (__float_as_uint(l7) & 0xFFFF0000u));
    }

    const bf16x8 bh0 = Bhi[(kk * 2 + 0) * 64 + lane];
    const bf16x8 bl0 = Blo[(kk * 2 + 0) * 64 + lane];
    const bf16x8 bh1 = Bhi[(kk * 2 + 1) * 64 + lane];
    const bf16x8 bl1 = Blo[(kk * 2 + 1) * 64 + lane];

    acc0 = __builtin_amdgcn_mfma_f32_16x16x32_bf16(ah.b, bh0, acc0, 0, 0, 0);
    acc0 = __builtin_amdgcn_mfma_f32_16x16x32_bf16(ah.b, bl0, acc0, 0, 0, 0);
    acc0 = __builtin_amdgcn_mfma_f32_16x16x32_bf16(al.b, bh0, acc0, 0, 0, 0);
    acc1 = __builtin_amdgcn_mfma_f32_16x16x32_bf16(ah.b, bh1, acc1, 0, 0, 0);
    acc1 = __builtin_amdgcn_mfma_f32_16x16x32_bf16(ah.b, bl1, acc1, 0, 0, 0);
    acc1 = __builtin_amdgcn_mfma_f32_16x16x32_bf16(al.b, bh1, acc1, 0, 0, 0);
  }

  // epilogue: C/D layout col=lane&15 (=n), row=quad*4+r (=t offset)
  const float b0 = bcat[n];
  const float b1 = bcat[16 + n];
#pragma unroll
  for (int r = 0; r < 4; ++r) {
    const int t = t0 + quad * 4 + r;
    float* dst = Af + (size_t)t * 64;
    const float ang0 = (acc0[r] + b0) * INV4PI;
    ((float2*)(dst + 2 * n))[0] = make_float2(COS_REV(ang0), SIN_REV(ang0));
    const float ang1 = (acc1[r] + b1) * INV4PI;
    ((float2*)(dst + 2 * (16 + n)))[0] = make_float2(COS_REV(ang1), SIN_REV(ang1));
  }
}

// ---------------------------------------------------------------------------
// Kernel 2: S[qq] = sum_d W_gate[q, DIN+d] * INV4PI; also bcat[qq] = b_gate[q]
// ---------------------------------------------------------------------------
__global__ __launch_bounds__(64) void rowsum_kernel(
    const float* __restrict__ Wf, const float* __restrict__ Wi,
    const float* __restrict__ Wu, const float* __restrict__ Wo,
    const float* __restrict__ bf, const float* __restrict__ bi,
    const float* __restrict__ bu, const float* __restrict__ bo,
    float* __restrict__ S, float* __restrict__ bcat) {
  const int b    = blockIdx.x;
  const int gate = b >> 3;
  const int q    = b & 7;
  const int lane = threadIdx.x;
  const float* W = (gate == 0) ? Wf : (gate == 1) ? Wi : (gate == 2) ? Wu : Wo;
  const float* bg = (gate == 0) ? bf : (gate == 1) ? bi : (gate == 2) ? bu : bo;
  const float4* row = (const float4*)(W + (size_t)q * DTOT + DIN);
  float acc = 0.f;
#pragma unroll
  for (int j = 0; j < 8; ++j) {
    float4 w4 = row[lane + 64 * j];
    acc += w4.x + w4.y + w4.z + w4.w;
  }
#pragma unroll
  for (int off = 32; off > 0; off >>= 1) acc += __shfl_xor(acc, off);
  if (lane == 0) {
    S[b] = acc * INV4PI;
    bcat[b] = bg[q];
  }
}

// ---------------------------------------------------------------------------
// Kernel 3: chunk-parallel scan (R5-verified). Block b outputs [b*CH, b*CH+CH)
// after WU warmup steps from (c,h)=(0,0) — the cell contracts at <=0.73/step.
// ---------------------------------------------------------------------------
__global__ __launch_bounds__(64) void scan_kernel(
    const float4* __restrict__ A4, const float* __restrict__ S,
    float* __restrict__ hbuf, float* __restrict__ cfin) {
  const int blk  = blockIdx.x;
  const int lane = threadIdx.x;
  const int li = lane & 15;
  const int g  = li & 3;
  const int j  = li >> 2;
  const int m  = 4 * g + j;

  const int tout0  = blk * CH;
  int tstart = tout0 - WU;
  if (tstart < 0) tstart = 0;
  const int warm_groups = (tout0 - tstart) >> 3;

  const float k1 = S[8 * g + 2 * j]     * TWOPI;
  const float k2 = S[8 * g + 2 * j + 1] * TWOPI;
  const float k1s = k1 * k1, k2s = k2 * k2;
  const float K2h  = 0.5f * (k1s + k2s);
  const float P12  = k1 * k2;
  const float C4   = (k1s * k1s + k2s * k2s) * (1.f / 24.f) + 0.25f * k1s * k2s;
  const float K26  = (k1s + k2s) * (1.f / 6.f);
  const float c12a = 0.5f * k1s + (1.f / 6.f) * k2s;
  const float c12b = 0.5f * k2s + (1.f / 6.f) * k1s;

  const bool isT = (g == 2);   // update gate -> tanh; others sigmoid
  const float d0 = isT ? 0.f          : 0.5f;
  const float d1 = isT ? 0.9999864f   : 0.25f;
  const float d3 = isT ? -0.3329971f  : -1.f / 48.f;
  const float d5 = isT ? 0.1309016f   : 1.f / 480.f;
  const float d7 = isT ? -0.0463194f  : -17.f / 80640.f;
  const float d9 = isT ? 0.0100394f   : 31.f / 1451520.f;

  float c = 0.f, h = 0.f;

  float4 buf[8];
#pragma unroll
  for (int p = 0; p < 8; ++p) buf[p] = A4[(size_t)(tstart + p) * 16 + m];

  auto step = [&](int p, int t) {
    const float4 D = buf[p];
    int tp = t + 8;
    if (tp > T_STEPS - 1) tp = T_STEPS - 1;
    buf[p] = A4[(size_t)tp * 16 + m];          // 8-deep register prefetch

    const float cc = D.x * D.z, ss = D.y * D.w;
    const float cs = D.x * D.w, sc = D.y * D.z;
    const float sp   = ss * P12;
    const float a0   = cc;
    const float a1   = fmaf(-K2h, cc, sp);
    const float a2   = fmaf(C4, cc, -(sp * K26));
    const float csk2 = cs * k2, sck1 = sc * k1;
    const float b0   = -(csk2 + sck1);
    const float b1   = fmaf(csk2, c12a, sck1 * c12b);

    const float u  = h * h;
    const float w3 = fmaf(b1, u, b0);
    const float w1 = fmaf(a2, u, a1);
    const float w2 = fmaf(w1, u, a0);
    float pc = fmaf(h, w3, w2);                // cos(th1)*cos(th2)

    pc = DPP_MUL(pc, 0x124);                   // row_ror:4
    pc = DPP_MUL(pc, 0x128);                   // row_ror:8 -> prod of 8 cos

    const float tQ = pc * pc;                  // P
    const float xg = fmaf(2.f, tQ, -1.f);      // 2P-1
    const float u2 = xg * xg;
    float wp = fmaf(d9, u2, d7);
    wp = fmaf(wp, u2, d5);
    wp = fmaf(wp, u2, d3);
    wp = fmaf(wp, u2, d1);
    const float gv = fmaf(xg, wp, d0);

    const float f_b = DPP_MOV(gv, 0x00);
    const float i_b = DPP_MOV(gv, 0x55);
    const float g_b = DPP_MOV(gv, 0xAA);
    const float o_b = DPP_MOV(gv, 0xFF);

    c = fmaf(f_b, c, i_b * g_b);
    const float u3 = c * c;                    // tanh(c): Pade[5/4]
    const float nn = u3 + 105.f;
    const float Pn = fmaf(u3, nn, 945.f);
    const float q2 = fmaf(15.f, u3, 420.f);
    const float Qd = fmaf(u3, q2, 945.f);
    const float rc = RCPF(Qd);
    const float th = (c * Pn) * rc;
    h = o_b * th;
  };

  for (int gI = 0; gI < warm_groups; ++gI) {
    const int tb = tstart + gI * 8;
#pragma unroll
    for (int p = 0; p < 8; ++p) step(p, tb + p);
  }

  float4* Hout = (float4*)(hbuf + tout0);
  float4 hacc;
  for (int gI = 0; gI < CH / 8; ++gI) {
    const int tb = tout0 + gI * 8;
#pragma unroll
    for (int p = 0; p < 8; ++p) {
      step(p, tb + p);
      if ((p & 3) == 0)      hacc.x = h;
      else if ((p & 3) == 1) hacc.y = h;
      else if ((p & 3) == 2) hacc.z = h;
      else {
        hacc.w = h;
        if (lane == 0) Hout[(gI * 8 + p - 3) >> 2] = hacc;
      }
    }
  }
  if (blk == NB - 1 && lane == 0) cfin[0] = c;
}

// ---------------------------------------------------------------------------
// Kernel 4: broadcast h_t over DH, plus hx / cx tails.
// ---------------------------------------------------------------------------
__global__ __launch_bounds__(256) void bcast_kernel(
    const float* __restrict__ hbuf, const float* __restrict__ cfin,
    float* __restrict__ out) {
  const int b = blockIdx.x;
  float v;
  size_t off;
  if (b < T_STEPS) {
    v = hbuf[b];
    off = (size_t)b * DH;
  } else if (b == T_STEPS) {
    v = hbuf[T_STEPS - 1];
    off = (size_t)T_STEPS * DH;
  } else {
    v = cfin[0];
    off = (size_t)T_STEPS * DH + DH;
  }
  const float4 v4 = make_float4(v, v, v, v);
  float4* dst = (float4*)(out + off);
  dst[threadIdx.x]       = v4;
  dst[threadIdx.x + 256] = v4;
}

extern "C" void kernel_launch(void* const* d_in, const int* in_sizes, int n_in,
                              void* d_out, int out_size, void* d_ws, size_t ws_size,
                              hipStream_t stream) {
  const float* x  = (const float*)d_in[0];
  const float* Wf = (const float*)d_in[1];
  const float* bf = (const float*)d_in[2];
  const float* Wi = (const float*)d_in[3];
  const float* bi = (const float*)d_in[4];
  const float* Wu = (const float*)d_in[5];
  const float* bu = (const float*)d_in[6];
  const float* Wo = (const float*)d_in[7];
  const float* bo = (const float*)d_in[8];
  float* out = (float*)d_out;

  // ws layout: Af[8192*64 f] | Bhi[128*64*8 us] | Blo[same] | S[32 f] |
  //            bcat[32 f] | hbuf[8192 f] | cfin[1 f]
  char* wsb = (char*)d_ws;
  float*          Af   = (float*)wsb;                       // 2 MiB
  unsigned short* BhiS = (unsigned short*)(wsb + (size_t)T_STEPS * 64 * 4);
  unsigned short* BloS = BhiS + (size_t)128 * 64 * 8;       // +128 KiB each
  float*          S    = (float*)(BloS + (size_t)128 * 64 * 8);
  float*          bcat = S + NQQ;
  float*          hbuf = bcat + NQQ;
  float*          cfin = hbuf + T_STEPS;

  hipLaunchKernelGGL(prep_kernel, dim3(128), dim3(64), 0, stream,
                     Wf, Wi, Wu, Wo, BhiS, BloS);
  hipLaunchKernelGGL(rowsum_kernel, dim3(NQQ), dim3(64), 0, stream,
                     Wf, Wi, Wu, Wo, bf, bi, bu, bo, S, bcat);
  hipLaunchKernelGGL(mfma_gemm_kernel, dim3(T_STEPS / 16), dim3(64), 0, stream,
                     x, (const bf16x8*)BhiS, (const bf16x8*)BloS, bcat, Af);
  hipLaunchKernelGGL(scan_kernel, dim3(NB), dim3(64), 0, stream,
                     (const float4*)Af, S, hbuf, cfin);
  hipLaunchKernelGGL(bcast_kernel, dim3(T_STEPS + 2), dim3(256), 0, stream,
                     hbuf, cfin, out);
}

// Round 7
// 165.687 us; speedup vs baseline: 7.7845x; 1.1773x over previous
//
#include <hip/hip_runtime.h>

#define T_STEPS 8192
#define DIN     2048
#define DH      2048
#define DTOT    4096
#define QG      8
#define NQQ     32

#define CH      64     // output steps per scan block
#define WU      96     // warmup steps (contraction <=0.73/step; 0.85^96 ~ 6e-7)
#define NB      (T_STEPS / CH)
#define KSTEPS  (DIN / 32)   // 64 MFMA K-steps
#define KW      (KSTEPS / 4) // 16 K-steps per wave (4-way K-split)

#define INV4PI  0.0795774715459476678f
#define TWOPI   6.28318530717958648f

#if __has_builtin(__builtin_amdgcn_cosf)
#define COS_REV(x) __builtin_amdgcn_cosf(x)          // cos(2*pi*x)
#else
#define COS_REV(x) __cosf((x) * TWOPI)
#endif
#if __has_builtin(__builtin_amdgcn_sinf)
#define SIN_REV(x) __builtin_amdgcn_sinf(x)          // sin(2*pi*x)
#else
#define SIN_REV(x) __sinf((x) * TWOPI)
#endif
#if __has_builtin(__builtin_amdgcn_rcpf)
#define RCPF(x) __builtin_amdgcn_rcpf(x)
#else
#define RCPF(x) (1.0f / (x))
#endif

#define DPP_MUL(x, ctrl)                                                        \
  ((x) * __int_as_float(__builtin_amdgcn_update_dpp(                            \
             __float_as_int(x), __float_as_int(x), (ctrl), 0xF, 0xF, false)))
#define DPP_MOV(x, ctrl)                                                        \
  __int_as_float(__builtin_amdgcn_update_dpp(                                   \
      __float_as_int(x), __float_as_int(x), (ctrl), 0xF, 0xF, false))

typedef short bf16x8 __attribute__((ext_vector_type(8)));
typedef float f32x4  __attribute__((ext_vector_type(4)));
typedef int   i32x4  __attribute__((ext_vector_type(4)));
union Pack8 { i32x4 i; bf16x8 b; };

__device__ __forceinline__ unsigned short f2bf_rne(float f) {
  unsigned u = __float_as_uint(f);
  return (unsigned short)((u + 0x7FFFu + ((u >> 16) & 1u)) >> 16);
}

// ---------------------------------------------------------------------------
// Kernel 0 (prep): pack W gate rows (input part, k<2048) into MFMA B-operand
// fragments, hi/lo bf16 split (RNE). Block blk = kk*2+nt (kk=K-step, nt=N-
// tile); lane: n=lane&15 -> qq=nt*16+n (qq = 8*gate+q), k = kk*32+quad*8+j.
// ---------------------------------------------------------------------------
__global__ __launch_bounds__(64) void prep_kernel(
    const float* __restrict__ Wf, const float* __restrict__ Wi,
    const float* __restrict__ Wu, const float* __restrict__ Wo,
    unsigned short* __restrict__ BhiS, unsigned short* __restrict__ BloS) {
  const int blk  = blockIdx.x;
  const int kk   = blk >> 1;
  const int nt   = blk & 1;
  const int lane = threadIdx.x;
  const int n    = lane & 15;
  const int quad = lane >> 4;
  const int qq   = nt * 16 + n;
  const int gate = qq >> 3;
  const int q    = qq & 7;
  const float* W = (gate == 0) ? Wf : (gate == 1) ? Wi : (gate == 2) ? Wu : Wo;
  const float4* src = (const float4*)(W + (size_t)q * DTOT + kk * 32 + quad * 8);
  const float4 s0 = src[0];
  const float4 s1 = src[1];
  const float wv[8] = {s0.x, s0.y, s0.z, s0.w, s1.x, s1.y, s1.z, s1.w};
  const size_t base = ((size_t)blk * 64 + lane) * 8;
#pragma unroll
  for (int j = 0; j < 8; ++j) {
    const unsigned short h = f2bf_rne(wv[j]);
    const float hf = __uint_as_float(((unsigned)h) << 16);
    const unsigned short l = f2bf_rne(wv[j] - hf);
    BhiS[base + j] = h;
    BloS[base + j] = l;
  }
}

// ---------------------------------------------------------------------------
// Kernel 1 (MFMA gemm): one block (4 waves) per 16(M)x32(N) C-tile, 512
// blocks. Wave w accumulates K in [w*512,(w+1)*512) (4-way K-split -> 8
// waves/CU for latency hiding); LDS reduce; wave 0 epilogue emits
// Af[t][2*qq] = {cos, sin}. A split hi/lo bf16 on the fly (truncation),
// B from prep (RNE split); 3 MFMAs (hh+hl+lh) per (k-step, n-tile).
// ---------------------------------------------------------------------------
__global__ __launch_bounds__(256) void mfma_gemm_kernel(
    const float* __restrict__ x,
    const bf16x8* __restrict__ Bhi, const bf16x8* __restrict__ Blo,
    const float* __restrict__ bcat,
    float* __restrict__ Af) {
  const int tid  = threadIdx.x;
  const int wave = tid >> 6;
  const int lane = tid & 63;
  const int t0   = blockIdx.x * 16;
  const int n    = lane & 15;       // A: m-index loader; C: n-index
  const int quad = lane >> 4;
  const float* xrow = x + (size_t)(t0 + n) * DIN + quad * 8;

  f32x4 acc0 = {0.f, 0.f, 0.f, 0.f};
  f32x4 acc1 = {0.f, 0.f, 0.f, 0.f};

  const int kk0 = wave * KW;
#pragma unroll 4
  for (int kki = 0; kki < KW; ++kki) {
    const int kk = kk0 + kki;
    const float4* p = (const float4*)(xrow + kk * 32);
    const float4 a0 = p[0];
    const float4 a1 = p[1];

    // truncation hi/lo split + pack (pairs in k order)
    Pack8 ah, al;
    {
      const unsigned u0 = __float_as_uint(a0.x), u1 = __float_as_uint(a0.y);
      const unsigned u2 = __float_as_uint(a0.z), u3 = __float_as_uint(a0.w);
      const unsigned u4 = __float_as_uint(a1.x), u5 = __float_as_uint(a1.y);
      const unsigned u6 = __float_as_uint(a1.z), u7 = __float_as_uint(a1.w);
      ah.i[0] = (int)((u0 >> 16) | (u1 & 0xFFFF0000u));
      ah.i[1] = (int)((u2 >> 16) | (u3 & 0xFFFF0000u));
      ah.i[2] = (int)((u4 >> 16) | (u5 & 0xFFFF0000u));
      ah.i[3] = (int)((u6 >> 16) | (u7 & 0xFFFF0000u));
      const float l0 = a0.x - __uint_as_float(u0 & 0xFFFF0000u);
      const float l1 = a0.y - __uint_as_float(u1 & 0xFFFF0000u);
      const float l2 = a0.z - __uint_as_float(u2 & 0xFFFF0000u);
      const float l3 = a0.w - __uint_as_float(u3 & 0xFFFF0000u);
      const float l4 = a1.x - __uint_as_float(u4 & 0xFFFF0000u);
      const float l5 = a1.y - __uint_as_float(u5 & 0xFFFF0000u);
      const float l6 = a1.z - __uint_as_float(u6 & 0xFFFF0000u);
      const float l7 = a1.w - __uint_as_float(u7 & 0xFFFF0000u);
      al.i[0] = (int)((__float_as_uint(l0) >> 16) | (__float_as_uint(l1) & 0xFFFF0000u));
      al.i[1] = (int)((__float_as_uint(l2) >> 16) | (__float_as_uint(l3) & 0xFFFF0000u));
      al.i[2] = (int)((__float_as_uint(l4) >> 16) | (__float_as_uint(l5) & 0xFFFF0000u));
      al.i[3] = (int)((__float_as_uint(l6) >> 16) | (__float_as_uint(l7) & 0xFFFF0000u));
    }

    const bf16x8 bh0 = Bhi[(kk * 2 + 0) * 64 + lane];
    const bf16x8 bl0 = Blo[(kk * 2 + 0) * 64 + lane];
    const bf16x8 bh1 = Bhi[(kk * 2 + 1) * 64 + lane];
    const bf16x8 bl1 = Blo[(kk * 2 + 1) * 64 + lane];

    acc0 = __builtin_amdgcn_mfma_f32_16x16x32_bf16(ah.b, bh0, acc0, 0, 0, 0);
    acc0 = __builtin_amdgcn_mfma_f32_16x16x32_bf16(ah.b, bl0, acc0, 0, 0, 0);
    acc0 = __builtin_amdgcn_mfma_f32_16x16x32_bf16(al.b, bh0, acc0, 0, 0, 0);
    acc1 = __builtin_amdgcn_mfma_f32_16x16x32_bf16(ah.b, bh1, acc1, 0, 0, 0);
    acc1 = __builtin_amdgcn_mfma_f32_16x16x32_bf16(ah.b, bl1, acc1, 0, 0, 0);
    acc1 = __builtin_amdgcn_mfma_f32_16x16x32_bf16(al.b, bh1, acc1, 0, 0, 0);
  }

  // cross-wave K reduction in LDS
  __shared__ f32x4 red[2][4][64];
  red[0][wave][lane] = acc0;
  red[1][wave][lane] = acc1;
  __syncthreads();
  if (wave == 0) {
    acc0 = red[0][0][lane] + red[0][1][lane] + red[0][2][lane] + red[0][3][lane];
    acc1 = red[1][0][lane] + red[1][1][lane] + red[1][2][lane] + red[1][3][lane];

    // epilogue: C/D layout col=lane&15 (=n), row=quad*4+r (=t offset)
    const float b0 = bcat[n];
    const float b1 = bcat[16 + n];
#pragma unroll
    for (int r = 0; r < 4; ++r) {
      const int t = t0 + quad * 4 + r;
      float* dst = Af + (size_t)t * 64;
      const float ang0 = (acc0[r] + b0) * INV4PI;
      ((float2*)(dst + 2 * n))[0] = make_float2(COS_REV(ang0), SIN_REV(ang0));
      const float ang1 = (acc1[r] + b1) * INV4PI;
      ((float2*)(dst + 2 * (16 + n)))[0] = make_float2(COS_REV(ang1), SIN_REV(ang1));
    }
  }
}

// ---------------------------------------------------------------------------
// Kernel 2: S[qq] = sum_d W_gate[q, DIN+d] * INV4PI; also bcat[qq] = b_gate[q]
// ---------------------------------------------------------------------------
__global__ __launch_bounds__(64) void rowsum_kernel(
    const float* __restrict__ Wf, const float* __restrict__ Wi,
    const float* __restrict__ Wu, const float* __restrict__ Wo,
    const float* __restrict__ bf, const float* __restrict__ bi,
    const float* __restrict__ bu, const float* __restrict__ bo,
    float* __restrict__ S, float* __restrict__ bcat) {
  const int b    = blockIdx.x;
  const int gate = b >> 3;
  const int q    = b & 7;
  const int lane = threadIdx.x;
  const float* W = (gate == 0) ? Wf : (gate == 1) ? Wi : (gate == 2) ? Wu : Wo;
  const float* bg = (gate == 0) ? bf : (gate == 1) ? bi : (gate == 2) ? bu : bo;
  const float4* row = (const float4*)(W + (size_t)q * DTOT + DIN);
  float acc = 0.f;
#pragma unroll
  for (int j = 0; j < 8; ++j) {
    float4 w4 = row[lane + 64 * j];
    acc += w4.x + w4.y + w4.z + w4.w;
  }
#pragma unroll
  for (int off = 32; off > 0; off >>= 1) acc += __shfl_xor(acc, off);
  if (lane == 0) {
    S[b] = acc * INV4PI;
    bcat[b] = bg[q];
  }
}

// ---------------------------------------------------------------------------
// Kernel 3: chunk-parallel scan (R5-verified). Block b outputs [b*CH, b*CH+CH)
// after WU warmup steps from (c,h)=(0,0) — the cell contracts at <=0.73/step.
// ---------------------------------------------------------------------------
__global__ __launch_bounds__(64) void scan_kernel(
    const float4* __restrict__ A4, const float* __restrict__ S,
    float* __restrict__ hbuf, float* __restrict__ cfin) {
  const int blk  = blockIdx.x;
  const int lane = threadIdx.x;
  const int li = lane & 15;
  const int g  = li & 3;
  const int j  = li >> 2;
  const int m  = 4 * g + j;

  const int tout0  = blk * CH;
  int tstart = tout0 - WU;
  if (tstart < 0) tstart = 0;
  const int warm_groups = (tout0 - tstart) >> 3;

  const float k1 = S[8 * g + 2 * j]     * TWOPI;
  const float k2 = S[8 * g + 2 * j + 1] * TWOPI;
  const float k1s = k1 * k1, k2s = k2 * k2;
  const float K2h  = 0.5f * (k1s + k2s);
  const float P12  = k1 * k2;
  const float C4   = (k1s * k1s + k2s * k2s) * (1.f / 24.f) + 0.25f * k1s * k2s;
  const float K26  = (k1s + k2s) * (1.f / 6.f);
  const float c12a = 0.5f * k1s + (1.f / 6.f) * k2s;
  const float c12b = 0.5f * k2s + (1.f / 6.f) * k1s;

  const bool isT = (g == 2);   // update gate -> tanh; others sigmoid
  const float d0 = isT ? 0.f          : 0.5f;
  const float d1 = isT ? 0.9999864f   : 0.25f;
  const float d3 = isT ? -0.3329971f  : -1.f / 48.f;
  const float d5 = isT ? 0.1309016f   : 1.f / 480.f;
  const float d7 = isT ? -0.0463194f  : -17.f / 80640.f;
  const float d9 = isT ? 0.0100394f   : 31.f / 1451520.f;

  float c = 0.f, h = 0.f;

  float4 buf[8];
#pragma unroll
  for (int p = 0; p < 8; ++p) buf[p] = A4[(size_t)(tstart + p) * 16 + m];

  auto step = [&](int p, int t) {
    const float4 D = buf[p];
    int tp = t + 8;
    if (tp > T_STEPS - 1) tp = T_STEPS - 1;
    buf[p] = A4[(size_t)tp * 16 + m];          // 8-deep register prefetch

    const float cc = D.x * D.z, ss = D.y * D.w;
    const float cs = D.x * D.w, sc = D.y * D.z;
    const float sp   = ss * P12;
    const float a0   = cc;
    const float a1   = fmaf(-K2h, cc, sp);
    const float a2   = fmaf(C4, cc, -(sp * K26));
    const float csk2 = cs * k2, sck1 = sc * k1;
    const float b0   = -(csk2 + sck1);
    const float b1   = fmaf(csk2, c12a, sck1 * c12b);

    const float u  = h * h;
    const float w3 = fmaf(b1, u, b0);
    const float w1 = fmaf(a2, u, a1);
    const float w2 = fmaf(w1, u, a0);
    float pc = fmaf(h, w3, w2);                // cos(th1)*cos(th2)

    pc = DPP_MUL(pc, 0x124);                   // row_ror:4
    pc = DPP_MUL(pc, 0x128);                   // row_ror:8 -> prod of 8 cos

    const float tQ = pc * pc;                  // P
    const float xg = fmaf(2.f, tQ, -1.f);      // 2P-1
    const float u2 = xg * xg;
    float wp = fmaf(d9, u2, d7);
    wp = fmaf(wp, u2, d5);
    wp = fmaf(wp, u2, d3);
    wp = fmaf(wp, u2, d1);
    const float gv = fmaf(xg, wp, d0);

    const float f_b = DPP_MOV(gv, 0x00);
    const float i_b = DPP_MOV(gv, 0x55);
    const float g_b = DPP_MOV(gv, 0xAA);
    const float o_b = DPP_MOV(gv, 0xFF);

    c = fmaf(f_b, c, i_b * g_b);
    const float u3 = c * c;                    // tanh(c): Pade[5/4]
    const float nn = u3 + 105.f;
    const float Pn = fmaf(u3, nn, 945.f);
    const float q2 = fmaf(15.f, u3, 420.f);
    const float Qd = fmaf(u3, q2, 945.f);
    const float rc = RCPF(Qd);
    const float th = (c * Pn) * rc;
    h = o_b * th;
  };

  for (int gI = 0; gI < warm_groups; ++gI) {
    const int tb = tstart + gI * 8;
#pragma unroll
    for (int p = 0; p < 8; ++p) step(p, tb + p);
  }

  float4* Hout = (float4*)(hbuf + tout0);
  float4 hacc;
  for (int gI = 0; gI < CH / 8; ++gI) {
    const int tb = tout0 + gI * 8;
#pragma unroll
    for (int p = 0; p < 8; ++p) {
      step(p, tb + p);
      if ((p & 3) == 0)      hacc.x = h;
      else if ((p & 3) == 1) hacc.y = h;
      else if ((p & 3) == 2) hacc.z = h;
      else {
        hacc.w = h;
        if (lane == 0) Hout[(gI * 8 + p - 3) >> 2] = hacc;
      }
    }
  }
  if (blk == NB - 1 && lane == 0) cfin[0] = c;
}

// ---------------------------------------------------------------------------
// Kernel 4: broadcast h_t over DH, plus hx / cx tails.
// ---------------------------------------------------------------------------
__global__ __launch_bounds__(256) void bcast_kernel(
    const float* __restrict__ hbuf, const float* __restrict__ cfin,
    float* __restrict__ out) {
  const int b = blockIdx.x;
  float v;
  size_t off;
  if (b < T_STEPS) {
    v = hbuf[b];
    off = (size_t)b * DH;
  } else if (b == T_STEPS) {
    v = hbuf[T_STEPS - 1];
    off = (size_t)T_STEPS * DH;
  } else {
    v = cfin[0];
    off = (size_t)T_STEPS * DH + DH;
  }
  const float4 v4 = make_float4(v, v, v, v);
  float4* dst = (float4*)(out + off);
  dst[threadIdx.x]       = v4;
  dst[threadIdx.x + 256] = v4;
}

extern "C" void kernel_launch(void* const* d_in, const int* in_sizes, int n_in,
                              void* d_out, int out_size, void* d_ws, size_t ws_size,
                              hipStream_t stream) {
  const float* x  = (const float*)d_in[0];
  const float* Wf = (const float*)d_in[1];
  const float* bf = (const float*)d_in[2];
  const float* Wi = (const float*)d_in[3];
  const float* bi = (const float*)d_in[4];
  const float* Wu = (const float*)d_in[5];
  const float* bu = (const float*)d_in[6];
  const float* Wo = (const float*)d_in[7];
  const float* bo = (const float*)d_in[8];
  float* out = (float*)d_out;

  // ws layout: Af[8192*64 f] | Bhi[128*64*8 us] | Blo[same] | S[32 f] |
  //            bcat[32 f] | hbuf[8192 f] | cfin[1 f]
  char* wsb = (char*)d_ws;
  float*          Af   = (float*)wsb;                       // 2 MiB
  unsigned short* BhiS = (unsigned short*)(wsb + (size_t)T_STEPS * 64 * 4);
  unsigned short* BloS = BhiS + (size_t)128 * 64 * 8;       // +128 KiB each
  float*          S    = (float*)(BloS + (size_t)128 * 64 * 8);
  float*          bcat = S + NQQ;
  float*          hbuf = bcat + NQQ;
  float*          cfin = hbuf + T_STEPS;

  hipLaunchKernelGGL(prep_kernel, dim3(128), dim3(64), 0, stream,
                     Wf, Wi, Wu, Wo, BhiS, BloS);
  hipLaunchKernelGGL(rowsum_kernel, dim3(NQQ), dim3(64), 0, stream,
                     Wf, Wi, Wu, Wo, bf, bi, bu, bo, S, bcat);
  hipLaunchKernelGGL(mfma_gemm_kernel, dim3(T_STEPS / 16), dim3(256), 0, stream,
                     x, (const bf16x8*)BhiS, (const bf16x8*)BloS, bcat, Af);
  hipLaunchKernelGGL(scan_kernel, dim3(NB), dim3(64), 0, stream,
                     (const float4*)Af, S, hbuf, cfin);
  hipLaunchKernelGGL(bcast_kernel, dim3(T_STEPS + 2), dim3(256), 0, stream,
                     hbuf, cfin, out);
}

// Round 8
// 152.872 us; speedup vs baseline: 8.4371x; 1.0838x over previous
//
#include <hip/hip_runtime.h>

#define T_STEPS 8192
#define DIN     2048
#define DH      2048
#define DTOT    4096
#define QG      8
#define NQQ     32

#define CH      64     // output steps per scan block
#define WU      64     // warmup steps (contraction <=0.8/step; 0.8^64 ~ 6e-7)
#define NB      (T_STEPS / CH)
#define KSTEPS  (DIN / 32)   // 64 MFMA K-steps
#define KW      (KSTEPS / 4) // 16 K-steps per wave (4-way K-split)

#define INV4PI  0.0795774715459476678f
#define TWOPI   6.28318530717958648f

#if __has_builtin(__builtin_amdgcn_cosf)
#define COS_REV(x) __builtin_amdgcn_cosf(x)          // cos(2*pi*x)
#else
#define COS_REV(x) __cosf((x) * TWOPI)
#endif
#if __has_builtin(__builtin_amdgcn_sinf)
#define SIN_REV(x) __builtin_amdgcn_sinf(x)          // sin(2*pi*x)
#else
#define SIN_REV(x) __sinf((x) * TWOPI)
#endif
#if __has_builtin(__builtin_amdgcn_rcpf)
#define RCPF(x) __builtin_amdgcn_rcpf(x)
#else
#define RCPF(x) (1.0f / (x))
#endif

#define DPP_MUL(x, ctrl)                                                        \
  ((x) * __int_as_float(__builtin_amdgcn_update_dpp(                            \
             __float_as_int(x), __float_as_int(x), (ctrl), 0xF, 0xF, false)))
#define DPP_MOV(x, ctrl)                                                        \
  __int_as_float(__builtin_amdgcn_update_dpp(                                   \
      __float_as_int(x), __float_as_int(x), (ctrl), 0xF, 0xF, false))

typedef short bf16x8 __attribute__((ext_vector_type(8)));
typedef float f32x4  __attribute__((ext_vector_type(4)));
typedef int   i32x4  __attribute__((ext_vector_type(4)));
union Pack8 { i32x4 i; bf16x8 b; };

__device__ __forceinline__ unsigned short f2bf_rne(float f) {
  unsigned u = __float_as_uint(f);
  return (unsigned short)((u + 0x7FFFu + ((u >> 16) & 1u)) >> 16);
}

// ---------------------------------------------------------------------------
// Kernel 0 (prep, merged): blocks 0..127 pack W input-part rows into MFMA
// B-operand fragments (hi/lo bf16 RNE split); blocks 128..159 compute the
// hidden-part row sums S[qq] and bcat[qq]. Wave-uniform branch.
// ---------------------------------------------------------------------------
__global__ __launch_bounds__(64) void prep_kernel(
    const float* __restrict__ Wf, const float* __restrict__ Wi,
    const float* __restrict__ Wu, const float* __restrict__ Wo,
    const float* __restrict__ bf, const float* __restrict__ bi,
    const float* __restrict__ bu, const float* __restrict__ bo,
    unsigned short* __restrict__ BhiS, unsigned short* __restrict__ BloS,
    float* __restrict__ S, float* __restrict__ bcat) {
  const int blk  = blockIdx.x;
  const int lane = threadIdx.x;
  if (blk < 128) {
    // ---- B-fragment packing: blk = kk*2+nt; lane: n=lane&15, quad=lane>>4
    const int kk   = blk >> 1;
    const int nt   = blk & 1;
    const int n    = lane & 15;
    const int quad = lane >> 4;
    const int qq   = nt * 16 + n;
    const int gate = qq >> 3;
    const int q    = qq & 7;
    const float* W = (gate == 0) ? Wf : (gate == 1) ? Wi : (gate == 2) ? Wu : Wo;
    const float4* src = (const float4*)(W + (size_t)q * DTOT + kk * 32 + quad * 8);
    const float4 s0 = src[0];
    const float4 s1 = src[1];
    const float wv[8] = {s0.x, s0.y, s0.z, s0.w, s1.x, s1.y, s1.z, s1.w};
    const size_t base = ((size_t)blk * 64 + lane) * 8;
#pragma unroll
    for (int j = 0; j < 8; ++j) {
      const unsigned short h = f2bf_rne(wv[j]);
      const float hf = __uint_as_float(((unsigned)h) << 16);
      const unsigned short l = f2bf_rne(wv[j] - hf);
      BhiS[base + j] = h;
      BloS[base + j] = l;
    }
  } else {
    // ---- row sums: b = blk-128 -> gate b>>3, q b&7
    const int b    = blk - 128;
    const int gate = b >> 3;
    const int q    = b & 7;
    const float* W  = (gate == 0) ? Wf : (gate == 1) ? Wi : (gate == 2) ? Wu : Wo;
    const float* bg = (gate == 0) ? bf : (gate == 1) ? bi : (gate == 2) ? bu : bo;
    const float4* row = (const float4*)(W + (size_t)q * DTOT + DIN);
    float acc = 0.f;
#pragma unroll
    for (int j = 0; j < 8; ++j) {
      float4 w4 = row[lane + 64 * j];
      acc += w4.x + w4.y + w4.z + w4.w;
    }
#pragma unroll
    for (int off = 32; off > 0; off >>= 1) acc += __shfl_xor(acc, off);
    if (lane == 0) {
      S[b] = acc * INV4PI;
      bcat[b] = bg[q];
    }
  }
}

// ---------------------------------------------------------------------------
// Kernel 1 (MFMA gemm): one block (4 waves) per 16(M)x32(N) C-tile, 512
// blocks. Wave w accumulates K in [w*512,(w+1)*512) (4-way K-split -> 8
// waves/CU); LDS reduce; wave 0 epilogue emits Af[t][2*qq] = {cos, sin}.
// A split hi/lo bf16 on the fly (truncation), B from prep (RNE split);
// 3 MFMAs (hh+hl+lh) per (k-step, n-tile) gives fp32-grade error.
// ---------------------------------------------------------------------------
__global__ __launch_bounds__(256) void mfma_gemm_kernel(
    const float* __restrict__ x,
    const bf16x8* __restrict__ Bhi, const bf16x8* __restrict__ Blo,
    const float* __restrict__ bcat,
    float* __restrict__ Af) {
  const int tid  = threadIdx.x;
  const int wave = tid >> 6;
  const int lane = tid & 63;
  const int t0   = blockIdx.x * 16;
  const int n    = lane & 15;       // A: m-index loader; C: n-index
  const int quad = lane >> 4;
  const float* xrow = x + (size_t)(t0 + n) * DIN + quad * 8;

  f32x4 acc0 = {0.f, 0.f, 0.f, 0.f};
  f32x4 acc1 = {0.f, 0.f, 0.f, 0.f};

  const int kk0 = wave * KW;
#pragma unroll 4
  for (int kki = 0; kki < KW; ++kki) {
    const int kk = kk0 + kki;
    const float4* p = (const float4*)(xrow + kk * 32);
    const float4 a0 = p[0];
    const float4 a1 = p[1];

    // truncation hi/lo split + pack (pairs in k order)
    Pack8 ah, al;
    {
      const unsigned u0 = __float_as_uint(a0.x), u1 = __float_as_uint(a0.y);
      const unsigned u2 = __float_as_uint(a0.z), u3 = __float_as_uint(a0.w);
      const unsigned u4 = __float_as_uint(a1.x), u5 = __float_as_uint(a1.y);
      const unsigned u6 = __float_as_uint(a1.z), u7 = __float_as_uint(a1.w);
      ah.i[0] = (int)((u0 >> 16) | (u1 & 0xFFFF0000u));
      ah.i[1] = (int)((u2 >> 16) | (u3 & 0xFFFF0000u));
      ah.i[2] = (int)((u4 >> 16) | (u5 & 0xFFFF0000u));
      ah.i[3] = (int)((u6 >> 16) | (u7 & 0xFFFF0000u));
      const float l0 = a0.x - __uint_as_float(u0 & 0xFFFF0000u);
      const float l1 = a0.y - __uint_as_float(u1 & 0xFFFF0000u);
      const float l2 = a0.z - __uint_as_float(u2 & 0xFFFF0000u);
      const float l3 = a0.w - __uint_as_float(u3 & 0xFFFF0000u);
      const float l4 = a1.x - __uint_as_float(u4 & 0xFFFF0000u);
      const float l5 = a1.y - __uint_as_float(u5 & 0xFFFF0000u);
      const float l6 = a1.z - __uint_as_float(u6 & 0xFFFF0000u);
      const float l7 = a1.w - __uint_as_float(u7 & 0xFFFF0000u);
      al.i[0] = (int)((__float_as_uint(l0) >> 16) | (__float_as_uint(l1) & 0xFFFF0000u));
      al.i[1] = (int)((__float_as_uint(l2) >> 16) | (__float_as_uint(l3) & 0xFFFF0000u));
      al.i[2] = (int)((__float_as_uint(l4) >> 16) | (__float_as_uint(l5) & 0xFFFF0000u));
      al.i[3] = (int)((__float_as_uint(l6) >> 16) | (__float_as_uint(l7) & 0xFFFF0000u));
    }

    const bf16x8 bh0 = Bhi[(kk * 2 + 0) * 64 + lane];
    const bf16x8 bl0 = Blo[(kk * 2 + 0) * 64 + lane];
    const bf16x8 bh1 = Bhi[(kk * 2 + 1) * 64 + lane];
    const bf16x8 bl1 = Blo[(kk * 2 + 1) * 64 + lane];

    acc0 = __builtin_amdgcn_mfma_f32_16x16x32_bf16(ah.b, bh0, acc0, 0, 0, 0);
    acc0 = __builtin_amdgcn_mfma_f32_16x16x32_bf16(ah.b, bl0, acc0, 0, 0, 0);
    acc0 = __builtin_amdgcn_mfma_f32_16x16x32_bf16(al.b, bh0, acc0, 0, 0, 0);
    acc1 = __builtin_amdgcn_mfma_f32_16x16x32_bf16(ah.b, bh1, acc1, 0, 0, 0);
    acc1 = __builtin_amdgcn_mfma_f32_16x16x32_bf16(ah.b, bl1, acc1, 0, 0, 0);
    acc1 = __builtin_amdgcn_mfma_f32_16x16x32_bf16(al.b, bh1, acc1, 0, 0, 0);
  }

  // cross-wave K reduction in LDS
  __shared__ f32x4 red[2][4][64];
  red[0][wave][lane] = acc0;
  red[1][wave][lane] = acc1;
  __syncthreads();
  if (wave == 0) {
    acc0 = red[0][0][lane] + red[0][1][lane] + red[0][2][lane] + red[0][3][lane];
    acc1 = red[1][0][lane] + red[1][1][lane] + red[1][2][lane] + red[1][3][lane];

    // epilogue: C/D layout col=lane&15 (=n), row=quad*4+r (=t offset)
    const float b0 = bcat[n];
    const float b1 = bcat[16 + n];
#pragma unroll
    for (int r = 0; r < 4; ++r) {
      const int t = t0 + quad * 4 + r;
      float* dst = Af + (size_t)t * 64;
      const float ang0 = (acc0[r] + b0) * INV4PI;
      ((float2*)(dst + 2 * n))[0] = make_float2(COS_REV(ang0), SIN_REV(ang0));
      const float ang1 = (acc1[r] + b1) * INV4PI;
      ((float2*)(dst + 2 * (16 + n)))[0] = make_float2(COS_REV(ang1), SIN_REV(ang1));
    }
  }
}

// ---------------------------------------------------------------------------
// Kernel 2: chunk-parallel scan + fused output broadcast. Block b outputs
// t in [b*CH, b*CH+CH) after WU warmup steps from (c,h)=(0,0) (cell
// contracts <=0.8/step). h is uniform across ALL 64 lanes (DPP ops are
// row-local), so every lane writes its 8 float4 slices of the 8 KB output
// row directly — coalesced 1 KB segments, no hbuf round-trip, no bcast
// kernel. Store-data quad alternates (2-step reuse gap > store latency).
// Last block also writes the hx / cx tail rows.
// ---------------------------------------------------------------------------
__global__ __launch_bounds__(64) void scan_kernel(
    const float4* __restrict__ A4, const float* __restrict__ S,
    float* __restrict__ out) {
  const int blk  = blockIdx.x;
  const int lane = threadIdx.x;
  const int li = lane & 15;
  const int g  = li & 3;
  const int j  = li >> 2;
  const int m  = 4 * g + j;

  const int tout0  = blk * CH;
  int tstart = tout0 - WU;
  if (tstart < 0) tstart = 0;
  const int warm_groups = (tout0 - tstart) >> 3;

  const float k1 = S[8 * g + 2 * j]     * TWOPI;
  const float k2 = S[8 * g + 2 * j + 1] * TWOPI;
  const float k1s = k1 * k1, k2s = k2 * k2;
  const float K2h  = 0.5f * (k1s + k2s);
  const float P12  = k1 * k2;
  const float C4   = (k1s * k1s + k2s * k2s) * (1.f / 24.f) + 0.25f * k1s * k2s;
  const float K26  = (k1s + k2s) * (1.f / 6.f);
  const float c12a = 0.5f * k1s + (1.f / 6.f) * k2s;
  const float c12b = 0.5f * k2s + (1.f / 6.f) * k1s;

  const bool isT = (g == 2);   // update gate -> tanh; others sigmoid
  const float d0 = isT ? 0.f          : 0.5f;
  const float d1 = isT ? 0.9999864f   : 0.25f;
  const float d3 = isT ? -0.3329971f  : -1.f / 48.f;
  const float d5 = isT ? 0.1309016f   : 1.f / 480.f;
  const float d7 = isT ? -0.0463194f  : -17.f / 80640.f;
  const float d9 = isT ? 0.0100394f   : 31.f / 1451520.f;

  float c = 0.f, h = 0.f;

  float4 buf[8];
#pragma unroll
  for (int p = 0; p < 8; ++p) buf[p] = A4[(size_t)(tstart + p) * 16 + m];

  auto step = [&](int p, int t) {
    const float4 D = buf[p];
    int tp = t + 8;
    if (tp > T_STEPS - 1) tp = T_STEPS - 1;
    buf[p] = A4[(size_t)tp * 16 + m];          // 8-deep register prefetch

    const float cc = D.x * D.z, ss = D.y * D.w;
    const float cs = D.x * D.w, sc = D.y * D.z;
    const float sp   = ss * P12;
    const float a0   = cc;
    const float a1   = fmaf(-K2h, cc, sp);
    const float a2   = fmaf(C4, cc, -(sp * K26));
    const float csk2 = cs * k2, sck1 = sc * k1;
    const float b0   = -(csk2 + sck1);
    const float b1   = fmaf(csk2, c12a, sck1 * c12b);

    const float u  = h * h;
    const float w3 = fmaf(b1, u, b0);
    const float w1 = fmaf(a2, u, a1);
    const float w2 = fmaf(w1, u, a0);
    float pc = fmaf(h, w3, w2);                // cos(th1)*cos(th2)

    pc = DPP_MUL(pc, 0x124);                   // row_ror:4
    pc = DPP_MUL(pc, 0x128);                   // row_ror:8 -> prod of 8 cos

    const float tQ = pc * pc;                  // P
    const float xg = fmaf(2.f, tQ, -1.f);      // 2P-1
    const float u2 = xg * xg;
    float wp = fmaf(d9, u2, d7);
    wp = fmaf(wp, u2, d5);
    wp = fmaf(wp, u2, d3);
    wp = fmaf(wp, u2, d1);
    const float gv = fmaf(xg, wp, d0);

    const float f_b = DPP_MOV(gv, 0x00);
    const float i_b = DPP_MOV(gv, 0x55);
    const float g_b = DPP_MOV(gv, 0xAA);
    const float o_b = DPP_MOV(gv, 0xFF);

    c = fmaf(f_b, c, i_b * g_b);
    const float u3 = c * c;                    // tanh(c): Pade[5/4]
    const float nn = u3 + 105.f;
    const float Pn = fmaf(u3, nn, 945.f);
    const float q2 = fmaf(15.f, u3, 420.f);
    const float Qd = fmaf(u3, q2, 945.f);
    const float rc = RCPF(Qd);
    const float th = (c * Pn) * rc;
    h = o_b * th;
  };

  // ---- warmup: no stores ----
  for (int gI = 0; gI < warm_groups; ++gI) {
    const int tb = tstart + gI * 8;
#pragma unroll
    for (int p = 0; p < 8; ++p) step(p, tb + p);
  }

  // ---- output: each step writes its full 8 KB row (h uniform over lanes) --
  float4 dreg[2];                // alternate store-data quads (2-step gap)
  for (int gI = 0; gI < CH / 8; ++gI) {
    const int tb = tout0 + gI * 8;
#pragma unroll
    for (int p = 0; p < 8; ++p) {
      step(p, tb + p);
      dreg[p & 1] = make_float4(h, h, h, h);
      float4* rowp = (float4*)(out + (size_t)(tb + p) * DH);
#pragma unroll
      for (int k = 0; k < 8; ++k) rowp[lane + 64 * k] = dreg[p & 1];
    }
  }

  // ---- tails: hx row and cx row ----
  if (blk == NB - 1) {
    const float4 hv = make_float4(h, h, h, h);
    const float4 cv = make_float4(c, c, c, c);
    float4* r1 = (float4*)(out + (size_t)T_STEPS * DH);
    float4* r2 = (float4*)(out + (size_t)T_STEPS * DH + DH);
#pragma unroll
    for (int k = 0; k < 8; ++k) {
      r1[lane + 64 * k] = hv;
      r2[lane + 64 * k] = cv;
    }
  }
}

extern "C" void kernel_launch(void* const* d_in, const int* in_sizes, int n_in,
                              void* d_out, int out_size, void* d_ws, size_t ws_size,
                              hipStream_t stream) {
  const float* x  = (const float*)d_in[0];
  const float* Wf = (const float*)d_in[1];
  const float* bf = (const float*)d_in[2];
  const float* Wi = (const float*)d_in[3];
  const float* bi = (const float*)d_in[4];
  const float* Wu = (const float*)d_in[5];
  const float* bu = (const float*)d_in[6];
  const float* Wo = (const float*)d_in[7];
  const float* bo = (const float*)d_in[8];
  float* out = (float*)d_out;

  // ws layout: Af[8192*64 f] | Bhi[128*64*8 us] | Blo[same] | S[32 f] | bcat[32 f]
  char* wsb = (char*)d_ws;
  float*          Af   = (float*)wsb;                       // 2 MiB
  unsigned short* BhiS = (unsigned short*)(wsb + (size_t)T_STEPS * 64 * 4);
  unsigned short* BloS = BhiS + (size_t)128 * 64 * 8;       // +128 KiB each
  float*          S    = (float*)(BloS + (size_t)128 * 64 * 8);
  float*          bcat = S + NQQ;

  hipLaunchKernelGGL(prep_kernel, dim3(160), dim3(64), 0, stream,
                     Wf, Wi, Wu, Wo, bf, bi, bu, bo, BhiS, BloS, S, bcat);
  hipLaunchKernelGGL(mfma_gemm_kernel, dim3(T_STEPS / 16), dim3(256), 0, stream,
                     x, (const bf16x8*)BhiS, (const bf16x8*)BloS, bcat, Af);
  hipLaunchKernelGGL(scan_kernel, dim3(NB), dim3(64), 0, stream,
                     (const float4*)Af, S, out);
}

// Round 10
// 143.877 us; speedup vs baseline: 8.9645x; 1.0625x over previous
//
#include <hip/hip_runtime.h>

#define T_STEPS 8192
#define DIN     2048
#define DH      2048
#define DTOT    4096
#define QG      8
#define NQQ     32

#define CH      32     // output steps per scan block
#define WU      48     // warmup steps (contraction <=0.73/step; 0.73^48 ~ 3e-7)
#define NB      (T_STEPS / CH)
#define KSTEPS  (DIN / 32)   // 64 MFMA K-steps
#define KW      (KSTEPS / 4) // 16 K-steps per wave (4-way K-split)

#define INV4PI  0.0795774715459476678f
#define TWOPI   6.28318530717958648f

#if __has_builtin(__builtin_amdgcn_cosf)
#define COS_REV(x) __builtin_amdgcn_cosf(x)          // cos(2*pi*x)
#else
#define COS_REV(x) __cosf((x) * TWOPI)
#endif
#if __has_builtin(__builtin_amdgcn_sinf)
#define SIN_REV(x) __builtin_amdgcn_sinf(x)          // sin(2*pi*x)
#else
#define SIN_REV(x) __sinf((x) * TWOPI)
#endif
#if __has_builtin(__builtin_amdgcn_rcpf)
#define RCPF(x) __builtin_amdgcn_rcpf(x)
#else
#define RCPF(x) (1.0f / (x))
#endif

#define DPP_MUL(x, ctrl)                                                        \
  ((x) * __int_as_float(__builtin_amdgcn_update_dpp(                            \
             __float_as_int(x), __float_as_int(x), (ctrl), 0xF, 0xF, false)))
#define DPP_MOV(x, ctrl)                                                        \
  __int_as_float(__builtin_amdgcn_update_dpp(                                   \
      __float_as_int(x), __float_as_int(x), (ctrl), 0xF, 0xF, false))

typedef short bf16x8 __attribute__((ext_vector_type(8)));
typedef float f32x4  __attribute__((ext_vector_type(4)));
typedef int   i32x4  __attribute__((ext_vector_type(4)));
union Pack8 { i32x4 i; bf16x8 b; };

__device__ __forceinline__ unsigned short f2bf_rne(float f) {
  unsigned u = __float_as_uint(f);
  return (unsigned short)((u + 0x7FFFu + ((u >> 16) & 1u)) >> 16);
}

// ---------------------------------------------------------------------------
// Kernel 0 (prep, merged): blocks 0..127 pack W input-part rows into MFMA
// B-operand fragments (hi/lo bf16 RNE split); blocks 128..159 compute the
// hidden-part row sums S[qq] and bcat[qq]. Wave-uniform branch.
// ---------------------------------------------------------------------------
__global__ __launch_bounds__(64) void prep_kernel(
    const float* __restrict__ Wf, const float* __restrict__ Wi,
    const float* __restrict__ Wu, const float* __restrict__ Wo,
    const float* __restrict__ bf, const float* __restrict__ bi,
    const float* __restrict__ bu, const float* __restrict__ bo,
    unsigned short* __restrict__ BhiS, unsigned short* __restrict__ BloS,
    float* __restrict__ S, float* __restrict__ bcat) {
  const int blk  = blockIdx.x;
  const int lane = threadIdx.x;
  if (blk < 128) {
    const int kk   = blk >> 1;
    const int nt   = blk & 1;
    const int n    = lane & 15;
    const int quad = lane >> 4;
    const int qq   = nt * 16 + n;
    const int gate = qq >> 3;
    const int q    = qq & 7;
    const float* W = (gate == 0) ? Wf : (gate == 1) ? Wi : (gate == 2) ? Wu : Wo;
    const float4* src = (const float4*)(W + (size_t)q * DTOT + kk * 32 + quad * 8);
    const float4 s0 = src[0];
    const float4 s1 = src[1];
    const float wv[8] = {s0.x, s0.y, s0.z, s0.w, s1.x, s1.y, s1.z, s1.w};
    const size_t base = ((size_t)blk * 64 + lane) * 8;
#pragma unroll
    for (int j = 0; j < 8; ++j) {
      const unsigned short h = f2bf_rne(wv[j]);
      const float hf = __uint_as_float(((unsigned)h) << 16);
      const unsigned short l = f2bf_rne(wv[j] - hf);
      BhiS[base + j] = h;
      BloS[base + j] = l;
    }
  } else {
    const int b    = blk - 128;
    const int gate = b >> 3;
    const int q    = b & 7;
    const float* W  = (gate == 0) ? Wf : (gate == 1) ? Wi : (gate == 2) ? Wu : Wo;
    const float* bg = (gate == 0) ? bf : (gate == 1) ? bi : (gate == 2) ? bu : bo;
    const float4* row = (const float4*)(W + (size_t)q * DTOT + DIN);
    float acc = 0.f;
#pragma unroll
    for (int j = 0; j < 8; ++j) {
      float4 w4 = row[lane + 64 * j];
      acc += w4.x + w4.y + w4.z + w4.w;
    }
#pragma unroll
    for (int off = 32; off > 0; off >>= 1) acc += __shfl_xor(acc, off);
    if (lane == 0) {
      S[b] = acc * INV4PI;
      bcat[b] = bg[q];
    }
  }
}

// ---------------------------------------------------------------------------
// Kernel 1 (MFMA gemm): one block (4 waves) per 16(M)x32(N) C-tile, 512
// blocks. Wave w accumulates K in [w*512,(w+1)*512); LDS reduce; wave 0
// epilogue emits Af[t][2*qq] = {cos, sin}. A split hi/lo bf16 on the fly
// (truncation), B from prep (RNE split); 3 MFMAs (hh+hl+lh) per step.
// unroll 8: ~8 independent load batches in flight (latency-bound regime).
// ---------------------------------------------------------------------------
__global__ __launch_bounds__(256) void mfma_gemm_kernel(
    const float* __restrict__ x,
    const bf16x8* __restrict__ Bhi, const bf16x8* __restrict__ Blo,
    const float* __restrict__ bcat,
    float* __restrict__ Af) {
  const int tid  = threadIdx.x;
  const int wave = tid >> 6;
  const int lane = tid & 63;
  const int t0   = blockIdx.x * 16;
  const int n    = lane & 15;       // A: m-index loader; C: n-index
  const int quad = lane >> 4;
  const float* xrow = x + (size_t)(t0 + n) * DIN + quad * 8;

  f32x4 acc0 = {0.f, 0.f, 0.f, 0.f};
  f32x4 acc1 = {0.f, 0.f, 0.f, 0.f};

  const int kk0 = wave * KW;
#pragma unroll 8
  for (int kki = 0; kki < KW; ++kki) {
    const int kk = kk0 + kki;
    const float4* p = (const float4*)(xrow + kk * 32);
    const float4 a0 = p[0];
    const float4 a1 = p[1];

    // truncation hi/lo split + pack (pairs in k order)
    Pack8 ah, al;
    {
      const unsigned u0 = __float_as_uint(a0.x), u1 = __float_as_uint(a0.y);
      const unsigned u2 = __float_as_uint(a0.z), u3 = __float_as_uint(a0.w);
      const unsigned u4 = __float_as_uint(a1.x), u5 = __float_as_uint(a1.y);
      const unsigned u6 = __float_as_uint(a1.z), u7 = __float_as_uint(a1.w);
      ah.i[0] = (int)((u0 >> 16) | (u1 & 0xFFFF0000u));
      ah.i[1] = (int)((u2 >> 16) | (u3 & 0xFFFF0000u));
      ah.i[2] = (int)((u4 >> 16) | (u5 & 0xFFFF0000u));
      ah.i[3] = (int)((u6 >> 16) | (u7 & 0xFFFF0000u));
      const float l0 = a0.x - __uint_as_float(u0 & 0xFFFF0000u);
      const float l1 = a0.y - __uint_as_float(u1 & 0xFFFF0000u);
      const float l2 = a0.z - __uint_as_float(u2 & 0xFFFF0000u);
      const float l3 = a0.w - __uint_as_float(u3 & 0xFFFF0000u);
      const float l4 = a1.x - __uint_as_float(u4 & 0xFFFF0000u);
      const float l5 = a1.y - __uint_as_float(u5 & 0xFFFF0000u);
      const float l6 = a1.z - __uint_as_float(u6 & 0xFFFF0000u);
      const float l7 = a1.w - __uint_as_float(u7 & 0xFFFF0000u);
      al.i[0] = (int)((__float_as_uint(l0) >> 16) | (__float_as_uint(l1) & 0xFFFF0000u));
      al.i[1] = (int)((__float_as_uint(l2) >> 16) | (__float_as_uint(l3) & 0xFFFF0000u));
      al.i[2] = (int)((__float_as_uint(l4) >> 16) | (__float_as_uint(l5) & 0xFFFF0000u));
      al.i[3] = (int)((__float_as_uint(l6) >> 16) | (__float_as_uint(l7) & 0xFFFF0000u));
    }

    const bf16x8 bh0 = Bhi[(kk * 2 + 0) * 64 + lane];
    const bf16x8 bl0 = Blo[(kk * 2 + 0) * 64 + lane];
    const bf16x8 bh1 = Bhi[(kk * 2 + 1) * 64 + lane];
    const bf16x8 bl1 = Blo[(kk * 2 + 1) * 64 + lane];

    acc0 = __builtin_amdgcn_mfma_f32_16x16x32_bf16(ah.b, bh0, acc0, 0, 0, 0);
    acc0 = __builtin_amdgcn_mfma_f32_16x16x32_bf16(ah.b, bl0, acc0, 0, 0, 0);
    acc0 = __builtin_amdgcn_mfma_f32_16x16x32_bf16(al.b, bh0, acc0, 0, 0, 0);
    acc1 = __builtin_amdgcn_mfma_f32_16x16x32_bf16(ah.b, bh1, acc1, 0, 0, 0);
    acc1 = __builtin_amdgcn_mfma_f32_16x16x32_bf16(ah.b, bl1, acc1, 0, 0, 0);
    acc1 = __builtin_amdgcn_mfma_f32_16x16x32_bf16(al.b, bh1, acc1, 0, 0, 0);
  }

  // cross-wave K reduction in LDS
  __shared__ f32x4 red[2][4][64];
  red[0][wave][lane] = acc0;
  red[1][wave][lane] = acc1;
  __syncthreads();
  if (wave == 0) {
    acc0 = red[0][0][lane] + red[0][1][lane] + red[0][2][lane] + red[0][3][lane];
    acc1 = red[1][0][lane] + red[1][1][lane] + red[1][2][lane] + red[1][3][lane];

    // epilogue: C/D layout col=lane&15 (=n), row=quad*4+r (=t offset)
    const float b0 = bcat[n];
    const float b1 = bcat[16 + n];
#pragma unroll
    for (int r = 0; r < 4; ++r) {
      const int t = t0 + quad * 4 + r;
      float* dst = Af + (size_t)t * 64;
      const float ang0 = (acc0[r] + b0) * INV4PI;
      ((float2*)(dst + 2 * n))[0] = make_float2(COS_REV(ang0), SIN_REV(ang0));
      const float ang1 = (acc1[r] + b1) * INV4PI;
      ((float2*)(dst + 2 * (16 + n)))[0] = make_float2(COS_REV(ang1), SIN_REV(ang1));
    }
  }
}

// ---------------------------------------------------------------------------
// Kernel 2: chunk-parallel scan + fused output broadcast. Block b outputs
// t in [b*CH, b*CH+CH) after WU warmup steps from (c,h)=(0,0) (cell
// contracts <=0.73/step). h is uniform across ALL 64 lanes (DPP ops are
// row-local), so every lane writes its 8 f32x4 slices of the 8 KB output
// row directly — coalesced 1 KB segments, nontemporal (skip L2 alloc).
// Last block also writes the hx / cx tail rows.
// ---------------------------------------------------------------------------
__global__ __launch_bounds__(64) void scan_kernel(
    const float4* __restrict__ A4, const float* __restrict__ S,
    float* __restrict__ out) {
  const int blk  = blockIdx.x;
  const int lane = threadIdx.x;
  const int li = lane & 15;
  const int g  = li & 3;
  const int j  = li >> 2;
  const int m  = 4 * g + j;

  const int tout0  = blk * CH;
  int tstart = tout0 - WU;
  if (tstart < 0) tstart = 0;
  const int warm_groups = (tout0 - tstart) >> 3;

  const float k1 = S[8 * g + 2 * j]     * TWOPI;
  const float k2 = S[8 * g + 2 * j + 1] * TWOPI;
  const float k1s = k1 * k1, k2s = k2 * k2;
  const float K2h  = 0.5f * (k1s + k2s);
  const float P12  = k1 * k2;
  const float C4   = (k1s * k1s + k2s * k2s) * (1.f / 24.f) + 0.25f * k1s * k2s;
  const float K26  = (k1s + k2s) * (1.f / 6.f);
  const float c12a = 0.5f * k1s + (1.f / 6.f) * k2s;
  const float c12b = 0.5f * k2s + (1.f / 6.f) * k1s;

  const bool isT = (g == 2);   // update gate -> tanh; others sigmoid
  const float d0 = isT ? 0.f          : 0.5f;
  const float d1 = isT ? 0.9999864f   : 0.25f;
  const float d3 = isT ? -0.3329971f  : -1.f / 48.f;
  const float d5 = isT ? 0.1309016f   : 1.f / 480.f;
  const float d7 = isT ? -0.0463194f  : -17.f / 80640.f;
  const float d9 = isT ? 0.0100394f   : 31.f / 1451520.f;

  float c = 0.f, h = 0.f;

  float4 buf[8];
#pragma unroll
  for (int p = 0; p < 8; ++p) buf[p] = A4[(size_t)(tstart + p) * 16 + m];

  auto step = [&](int p, int t) {
    const float4 D = buf[p];
    int tp = t + 8;
    if (tp > T_STEPS - 1) tp = T_STEPS - 1;
    buf[p] = A4[(size_t)tp * 16 + m];          // 8-deep register prefetch

    const float cc = D.x * D.z, ss = D.y * D.w;
    const float cs = D.x * D.w, sc = D.y * D.z;
    const float sp   = ss * P12;
    const float a0   = cc;
    const float a1   = fmaf(-K2h, cc, sp);
    const float a2   = fmaf(C4, cc, -(sp * K26));
    const float csk2 = cs * k2, sck1 = sc * k1;
    const float b0   = -(csk2 + sck1);
    const float b1   = fmaf(csk2, c12a, sck1 * c12b);

    const float u  = h * h;
    const float w3 = fmaf(b1, u, b0);
    const float w1 = fmaf(a2, u, a1);
    const float w2 = fmaf(w1, u, a0);
    float pc = fmaf(h, w3, w2);                // cos(th1)*cos(th2)

    pc = DPP_MUL(pc, 0x124);                   // row_ror:4
    pc = DPP_MUL(pc, 0x128);                   // row_ror:8 -> prod of 8 cos

    const float tQ = pc * pc;                  // P
    const float xg = fmaf(2.f, tQ, -1.f);      // 2P-1
    const float u2 = xg * xg;
    float wp = fmaf(d9, u2, d7);
    wp = fmaf(wp, u2, d5);
    wp = fmaf(wp, u2, d3);
    wp = fmaf(wp, u2, d1);
    const float gv = fmaf(xg, wp, d0);

    const float f_b = DPP_MOV(gv, 0x00);
    const float i_b = DPP_MOV(gv, 0x55);
    const float g_b = DPP_MOV(gv, 0xAA);
    const float o_b = DPP_MOV(gv, 0xFF);

    c = fmaf(f_b, c, i_b * g_b);
    const float u3 = c * c;                    // tanh(c): Pade[5/4]
    const float nn = u3 + 105.f;
    const float Pn = fmaf(u3, nn, 945.f);
    const float q2 = fmaf(15.f, u3, 420.f);
    const float Qd = fmaf(u3, q2, 945.f);
    const float rc = RCPF(Qd);
    const float th = (c * Pn) * rc;
    h = o_b * th;
  };

  // ---- warmup: no stores ----
  for (int gI = 0; gI < warm_groups; ++gI) {
    const int tb = tstart + gI * 8;
#pragma unroll
    for (int p = 0; p < 8; ++p) step(p, tb + p);
  }

  // ---- output: each step writes its full 8 KB row (h uniform over lanes) --
  f32x4 dreg[2];                // alternate store-data quads (2-step gap)
  for (int gI = 0; gI < CH / 8; ++gI) {
    const int tb = tout0 + gI * 8;
#pragma unroll
    for (int p = 0; p < 8; ++p) {
      step(p, tb + p);
      dreg[p & 1] = (f32x4){h, h, h, h};
      f32x4* rowp = (f32x4*)(out + (size_t)(tb + p) * DH);
#pragma unroll
      for (int k = 0; k < 8; ++k)
        __builtin_nontemporal_store(dreg[p & 1], rowp + lane + 64 * k);
    }
  }

  // ---- tails: hx row and cx row ----
  if (blk == NB - 1) {
    const f32x4 hv = {h, h, h, h};
    const f32x4 cv = {c, c, c, c};
    f32x4* r1 = (f32x4*)(out + (size_t)T_STEPS * DH);
    f32x4* r2 = (f32x4*)(out + (size_t)T_STEPS * DH + DH);
#pragma unroll
    for (int k = 0; k < 8; ++k) {
      __builtin_nontemporal_store(hv, r1 + lane + 64 * k);
      __builtin_nontemporal_store(cv, r2 + lane + 64 * k);
    }
  }
}

extern "C" void kernel_launch(void* const* d_in, const int* in_sizes, int n_in,
                              void* d_out, int out_size, void* d_ws, size_t ws_size,
                              hipStream_t stream) {
  const float* x  = (const float*)d_in[0];
  const float* Wf = (const float*)d_in[1];
  const float* bf = (const float*)d_in[2];
  const float* Wi = (const float*)d_in[3];
  const float* bi = (const float*)d_in[4];
  const float* Wu = (const float*)d_in[5];
  const float* bu = (const float*)d_in[6];
  const float* Wo = (const float*)d_in[7];
  const float* bo = (const float*)d_in[8];
  float* out = (float*)d_out;

  // ws layout: Af[8192*64 f] | Bhi[128*64*8 us] | Blo[same] | S[32 f] | bcat[32 f]
  char* wsb = (char*)d_ws;
  float*          Af   = (float*)wsb;                       // 2 MiB
  unsigned short* BhiS = (unsigned short*)(wsb + (size_t)T_STEPS * 64 * 4);
  unsigned short* BloS = BhiS + (size_t)128 * 64 * 8;       // +128 KiB each
  float*          S    = (float*)(BloS + (size_t)128 * 64 * 8);
  float*          bcat = S + NQQ;

  hipLaunchKernelGGL(prep_kernel, dim3(160), dim3(64), 0, stream,
                     Wf, Wi, Wu, Wo, bf, bi, bu, bo, BhiS, BloS, S, bcat);
  hipLaunchKernelGGL(mfma_gemm_kernel, dim3(T_STEPS / 16), dim3(256), 0, stream,
                     x, (const bf16x8*)BhiS, (const bf16x8*)BloS, bcat, Af);
  hipLaunchKernelGGL(scan_kernel, dim3(NB), dim3(64), 0, stream,
                     (const float4*)Af, S, out);
}

// Round 11
// 142.523 us; speedup vs baseline: 9.0497x; 1.0095x over previous
//
#include <hip/hip_runtime.h>

#define T_STEPS 8192
#define DIN     2048
#define DH      2048
#define DTOT    4096
#define QG      8
#define NQQ     32

#define CH      32     // output steps per scan block
#define WU      32     // warmup steps (contraction <=0.73/step; 0.73^32 ~ 4e-5)
#define NB      (T_STEPS / CH)
#define KSTEPS  (DIN / 32)   // 64 MFMA K-steps
#define KW      (KSTEPS / 8) // 8 K-steps per wave (8-way K-split)

#define INV4PI  0.0795774715459476678f
#define TWOPI   6.28318530717958648f

#if __has_builtin(__builtin_amdgcn_cosf)
#define COS_REV(x) __builtin_amdgcn_cosf(x)          // cos(2*pi*x)
#else
#define COS_REV(x) __cosf((x) * TWOPI)
#endif
#if __has_builtin(__builtin_amdgcn_sinf)
#define SIN_REV(x) __builtin_amdgcn_sinf(x)          // sin(2*pi*x)
#else
#define SIN_REV(x) __sinf((x) * TWOPI)
#endif
#if __has_builtin(__builtin_amdgcn_rcpf)
#define RCPF(x) __builtin_amdgcn_rcpf(x)
#else
#define RCPF(x) (1.0f / (x))
#endif

#define DPP_MUL(x, ctrl)                                                        \
  ((x) * __int_as_float(__builtin_amdgcn_update_dpp(                            \
             __float_as_int(x), __float_as_int(x), (ctrl), 0xF, 0xF, false)))
#define DPP_MOV(x, ctrl)                                                        \
  __int_as_float(__builtin_amdgcn_update_dpp(                                   \
      __float_as_int(x), __float_as_int(x), (ctrl), 0xF, 0xF, false))

typedef short bf16x8 __attribute__((ext_vector_type(8)));
typedef float f32x4  __attribute__((ext_vector_type(4)));
typedef int   i32x4  __attribute__((ext_vector_type(4)));
union Pack8 { i32x4 i; bf16x8 b; };

__device__ __forceinline__ unsigned short f2bf_rne(float f) {
  unsigned u = __float_as_uint(f);
  return (unsigned short)((u + 0x7FFFu + ((u >> 16) & 1u)) >> 16);
}

// ---------------------------------------------------------------------------
// Kernel 0 (prep, merged): blocks 0..127 pack W input-part rows into MFMA
// B-operand fragments (hi/lo bf16 RNE split); blocks 128..159 compute the
// hidden-part row sums S[qq] and bcat[qq]. Wave-uniform branch.
// ---------------------------------------------------------------------------
__global__ __launch_bounds__(64) void prep_kernel(
    const float* __restrict__ Wf, const float* __restrict__ Wi,
    const float* __restrict__ Wu, const float* __restrict__ Wo,
    const float* __restrict__ bf, const float* __restrict__ bi,
    const float* __restrict__ bu, const float* __restrict__ bo,
    unsigned short* __restrict__ BhiS, unsigned short* __restrict__ BloS,
    float* __restrict__ S, float* __restrict__ bcat) {
  const int blk  = blockIdx.x;
  const int lane = threadIdx.x;
  if (blk < 128) {
    const int kk   = blk >> 1;
    const int nt   = blk & 1;
    const int n    = lane & 15;
    const int quad = lane >> 4;
    const int qq   = nt * 16 + n;
    const int gate = qq >> 3;
    const int q    = qq & 7;
    const float* W = (gate == 0) ? Wf : (gate == 1) ? Wi : (gate == 2) ? Wu : Wo;
    const float4* src = (const float4*)(W + (size_t)q * DTOT + kk * 32 + quad * 8);
    const float4 s0 = src[0];
    const float4 s1 = src[1];
    const float wv[8] = {s0.x, s0.y, s0.z, s0.w, s1.x, s1.y, s1.z, s1.w};
    const size_t base = ((size_t)blk * 64 + lane) * 8;
#pragma unroll
    for (int j = 0; j < 8; ++j) {
      const unsigned short h = f2bf_rne(wv[j]);
      const float hf = __uint_as_float(((unsigned)h) << 16);
      const unsigned short l = f2bf_rne(wv[j] - hf);
      BhiS[base + j] = h;
      BloS[base + j] = l;
    }
  } else {
    const int b    = blk - 128;
    const int gate = b >> 3;
    const int q    = b & 7;
    const float* W  = (gate == 0) ? Wf : (gate == 1) ? Wi : (gate == 2) ? Wu : Wo;
    const float* bg = (gate == 0) ? bf : (gate == 1) ? bi : (gate == 2) ? bu : bo;
    const float4* row = (const float4*)(W + (size_t)q * DTOT + DIN);
    float acc = 0.f;
#pragma unroll
    for (int j = 0; j < 8; ++j) {
      float4 w4 = row[lane + 64 * j];
      acc += w4.x + w4.y + w4.z + w4.w;
    }
#pragma unroll
    for (int off = 32; off > 0; off >>= 1) acc += __shfl_xor(acc, off);
    if (lane == 0) {
      S[b] = acc * INV4PI;
      bcat[b] = bg[q];
    }
  }
}

// ---------------------------------------------------------------------------
// Kernel 1 (MFMA gemm): one block (8 waves, 512 thr) per 16(M)x32(N) C-tile,
// 512 blocks -> 4096 waves = 16 waves/CU. Wave w accumulates K in
// [w*256,(w+1)*256) (8-way K-split); LDS reduce; wave 0 epilogue emits
// Af[t][2*qq] = {cos, sin}. A split hi/lo bf16 on the fly (truncation),
// B from prep (RNE split); 3 MFMAs (hh+hl+lh) per (k-step, n-tile).
// ---------------------------------------------------------------------------
__global__ __launch_bounds__(512) void mfma_gemm_kernel(
    const float* __restrict__ x,
    const bf16x8* __restrict__ Bhi, const bf16x8* __restrict__ Blo,
    const float* __restrict__ bcat,
    float* __restrict__ Af) {
  const int tid  = threadIdx.x;
  const int wave = tid >> 6;
  const int lane = tid & 63;
  const int t0   = blockIdx.x * 16;
  const int n    = lane & 15;       // A: m-index loader; C: n-index
  const int quad = lane >> 4;
  const float* xrow = x + (size_t)(t0 + n) * DIN + quad * 8;

  f32x4 acc0 = {0.f, 0.f, 0.f, 0.f};
  f32x4 acc1 = {0.f, 0.f, 0.f, 0.f};

  const int kk0 = wave * KW;
#pragma unroll
  for (int kki = 0; kki < KW; ++kki) {
    const int kk = kk0 + kki;
    const float4* p = (const float4*)(xrow + kk * 32);
    const float4 a0 = p[0];
    const float4 a1 = p[1];

    // truncation hi/lo split + pack (pairs in k order)
    Pack8 ah, al;
    {
      const unsigned u0 = __float_as_uint(a0.x), u1 = __float_as_uint(a0.y);
      const unsigned u2 = __float_as_uint(a0.z), u3 = __float_as_uint(a0.w);
      const unsigned u4 = __float_as_uint(a1.x), u5 = __float_as_uint(a1.y);
      const unsigned u6 = __float_as_uint(a1.z), u7 = __float_as_uint(a1.w);
      ah.i[0] = (int)((u0 >> 16) | (u1 & 0xFFFF0000u));
      ah.i[1] = (int)((u2 >> 16) | (u3 & 0xFFFF0000u));
      ah.i[2] = (int)((u4 >> 16) | (u5 & 0xFFFF0000u));
      ah.i[3] = (int)((u6 >> 16) | (u7 & 0xFFFF0000u));
      const float l0 = a0.x - __uint_as_float(u0 & 0xFFFF0000u);
      const float l1 = a0.y - __uint_as_float(u1 & 0xFFFF0000u);
      const float l2 = a0.z - __uint_as_float(u2 & 0xFFFF0000u);
      const float l3 = a0.w - __uint_as_float(u3 & 0xFFFF0000u);
      const float l4 = a1.x - __uint_as_float(u4 & 0xFFFF0000u);
      const float l5 = a1.y - __uint_as_float(u5 & 0xFFFF0000u);
      const float l6 = a1.z - __uint_as_float(u6 & 0xFFFF0000u);
      const float l7 = a1.w - __uint_as_float(u7 & 0xFFFF0000u);
      al.i[0] = (int)((__float_as_uint(l0) >> 16) | (__float_as_uint(l1) & 0xFFFF0000u));
      al.i[1] = (int)((__float_as_uint(l2) >> 16) | (__float_as_uint(l3) & 0xFFFF0000u));
      al.i[2] = (int)((__float_as_uint(l4) >> 16) | (__float_as_uint(l5) & 0xFFFF0000u));
      al.i[3] = (int)((__float_as_uint(l6) >> 16) | (__float_as_uint(l7) & 0xFFFF0000u));
    }

    const bf16x8 bh0 = Bhi[(kk * 2 + 0) * 64 + lane];
    const bf16x8 bl0 = Blo[(kk * 2 + 0) * 64 + lane];
    const bf16x8 bh1 = Bhi[(kk * 2 + 1) * 64 + lane];
    const bf16x8 bl1 = Blo[(kk * 2 + 1) * 64 + lane];

    acc0 = __builtin_amdgcn_mfma_f32_16x16x32_bf16(ah.b, bh0, acc0, 0, 0, 0);
    acc0 = __builtin_amdgcn_mfma_f32_16x16x32_bf16(ah.b, bl0, acc0, 0, 0, 0);
    acc0 = __builtin_amdgcn_mfma_f32_16x16x32_bf16(al.b, bh0, acc0, 0, 0, 0);
    acc1 = __builtin_amdgcn_mfma_f32_16x16x32_bf16(ah.b, bh1, acc1, 0, 0, 0);
    acc1 = __builtin_amdgcn_mfma_f32_16x16x32_bf16(ah.b, bl1, acc1, 0, 0, 0);
    acc1 = __builtin_amdgcn_mfma_f32_16x16x32_bf16(al.b, bh1, acc1, 0, 0, 0);
  }

  // cross-wave K reduction in LDS (16 KB)
  __shared__ f32x4 red[2][8][64];
  red[0][wave][lane] = acc0;
  red[1][wave][lane] = acc1;
  __syncthreads();
  if (wave == 0) {
    acc0 = red[0][0][lane];
    acc1 = red[1][0][lane];
#pragma unroll
    for (int w = 1; w < 8; ++w) {
      acc0 += red[0][w][lane];
      acc1 += red[1][w][lane];
    }

    // epilogue: C/D layout col=lane&15 (=n), row=quad*4+r (=t offset)
    const float b0 = bcat[n];
    const float b1 = bcat[16 + n];
#pragma unroll
    for (int r = 0; r < 4; ++r) {
      const int t = t0 + quad * 4 + r;
      float* dst = Af + (size_t)t * 64;
      const float ang0 = (acc0[r] + b0) * INV4PI;
      ((float2*)(dst + 2 * n))[0] = make_float2(COS_REV(ang0), SIN_REV(ang0));
      const float ang1 = (acc1[r] + b1) * INV4PI;
      ((float2*)(dst + 2 * (16 + n)))[0] = make_float2(COS_REV(ang1), SIN_REV(ang1));
    }
  }
}

// ---------------------------------------------------------------------------
// Kernel 2: chunk-parallel scan + fused output broadcast. Block b outputs
// t in [b*CH, b*CH+CH) after WU warmup steps from (c,h)=(0,0) (cell
// contracts <=0.73/step). h is uniform across ALL 64 lanes (DPP ops are
// row-local), so every lane writes its 8 f32x4 slices of the 8 KB output
// row directly — coalesced 1 KB segments, nontemporal (skip L2 alloc).
// Last block also writes the hx / cx tail rows.
// ---------------------------------------------------------------------------
__global__ __launch_bounds__(64) void scan_kernel(
    const float4* __restrict__ A4, const float* __restrict__ S,
    float* __restrict__ out) {
  const int blk  = blockIdx.x;
  const int lane = threadIdx.x;
  const int li = lane & 15;
  const int g  = li & 3;
  const int j  = li >> 2;
  const int m  = 4 * g + j;

  const int tout0  = blk * CH;
  int tstart = tout0 - WU;
  if (tstart < 0) tstart = 0;
  const int warm_groups = (tout0 - tstart) >> 3;

  const float k1 = S[8 * g + 2 * j]     * TWOPI;
  const float k2 = S[8 * g + 2 * j + 1] * TWOPI;
  const float k1s = k1 * k1, k2s = k2 * k2;
  const float K2h  = 0.5f * (k1s + k2s);
  const float P12  = k1 * k2;
  const float C4   = (k1s * k1s + k2s * k2s) * (1.f / 24.f) + 0.25f * k1s * k2s;
  const float K26  = (k1s + k2s) * (1.f / 6.f);
  const float c12a = 0.5f * k1s + (1.f / 6.f) * k2s;
  const float c12b = 0.5f * k2s + (1.f / 6.f) * k1s;

  const bool isT = (g == 2);   // update gate -> tanh; others sigmoid
  const float d0 = isT ? 0.f          : 0.5f;
  const float d1 = isT ? 0.9999864f   : 0.25f;
  const float d3 = isT ? -0.3329971f  : -1.f / 48.f;
  const float d5 = isT ? 0.1309016f   : 1.f / 480.f;
  const float d7 = isT ? -0.0463194f  : -17.f / 80640.f;
  const float d9 = isT ? 0.0100394f   : 31.f / 1451520.f;

  float c = 0.f, h = 0.f;

  float4 buf[8];
#pragma unroll
  for (int p = 0; p < 8; ++p) buf[p] = A4[(size_t)(tstart + p) * 16 + m];

  auto step = [&](int p, int t) {
    const float4 D = buf[p];
    int tp = t + 8;
    if (tp > T_STEPS - 1) tp = T_STEPS - 1;
    buf[p] = A4[(size_t)tp * 16 + m];          // 8-deep register prefetch

    const float cc = D.x * D.z, ss = D.y * D.w;
    const float cs = D.x * D.w, sc = D.y * D.z;
    const float sp   = ss * P12;
    const float a0   = cc;
    const float a1   = fmaf(-K2h, cc, sp);
    const float a2   = fmaf(C4, cc, -(sp * K26));
    const float csk2 = cs * k2, sck1 = sc * k1;
    const float b0   = -(csk2 + sck1);
    const float b1   = fmaf(csk2, c12a, sck1 * c12b);

    const float u  = h * h;
    const float w3 = fmaf(b1, u, b0);
    const float w1 = fmaf(a2, u, a1);
    const float w2 = fmaf(w1, u, a0);
    float pc = fmaf(h, w3, w2);                // cos(th1)*cos(th2)

    pc = DPP_MUL(pc, 0x124);                   // row_ror:4
    pc = DPP_MUL(pc, 0x128);                   // row_ror:8 -> prod of 8 cos

    const float tQ = pc * pc;                  // P
    const float xg = fmaf(2.f, tQ, -1.f);      // 2P-1
    const float u2 = xg * xg;
    float wp = fmaf(d9, u2, d7);
    wp = fmaf(wp, u2, d5);
    wp = fmaf(wp, u2, d3);
    wp = fmaf(wp, u2, d1);
    const float gv = fmaf(xg, wp, d0);

    const float f_b = DPP_MOV(gv, 0x00);
    const float i_b = DPP_MOV(gv, 0x55);
    const float g_b = DPP_MOV(gv, 0xAA);
    const float o_b = DPP_MOV(gv, 0xFF);

    c = fmaf(f_b, c, i_b * g_b);
    const float u3 = c * c;                    // tanh(c): Pade[5/4]
    const float nn = u3 + 105.f;
    const float Pn = fmaf(u3, nn, 945.f);
    const float q2 = fmaf(15.f, u3, 420.f);
    const float Qd = fmaf(u3, q2, 945.f);
    const float rc = RCPF(Qd);
    const float th = (c * Pn) * rc;
    h = o_b * th;
  };

  // ---- warmup: no stores ----
  for (int gI = 0; gI < warm_groups; ++gI) {
    const int tb = tstart + gI * 8;
#pragma unroll
    for (int p = 0; p < 8; ++p) step(p, tb + p);
  }

  // ---- output: each step writes its full 8 KB row (h uniform over lanes) --
  f32x4 dreg[2];                // alternate store-data quads (2-step gap)
  for (int gI = 0; gI < CH / 8; ++gI) {
    const int tb = tout0 + gI * 8;
#pragma unroll
    for (int p = 0; p < 8; ++p) {
      step(p, tb + p);
      dreg[p & 1] = (f32x4){h, h, h, h};
      f32x4* rowp = (f32x4*)(out + (size_t)(tb + p) * DH);
#pragma unroll
      for (int k = 0; k < 8; ++k)
        __builtin_nontemporal_store(dreg[p & 1], rowp + lane + 64 * k);
    }
  }

  // ---- tails: hx row and cx row ----
  if (blk == NB - 1) {
    const f32x4 hv = {h, h, h, h};
    const f32x4 cv = {c, c, c, c};
    f32x4* r1 = (f32x4*)(out + (size_t)T_STEPS * DH);
    f32x4* r2 = (f32x4*)(out + (size_t)T_STEPS * DH + DH);
#pragma unroll
    for (int k = 0; k < 8; ++k) {
      __builtin_nontemporal_store(hv, r1 + lane + 64 * k);
      __builtin_nontemporal_store(cv, r2 + lane + 64 * k);
    }
  }
}

extern "C" void kernel_launch(void* const* d_in, const int* in_sizes, int n_in,
                              void* d_out, int out_size, void* d_ws, size_t ws_size,
                              hipStream_t stream) {
  const float* x  = (const float*)d_in[0];
  const float* Wf = (const float*)d_in[1];
  const float* bf = (const float*)d_in[2];
  const float* Wi = (const float*)d_in[3];
  const float* bi = (const float*)d_in[4];
  const float* Wu = (const float*)d_in[5];
  const float* bu = (const float*)d_in[6];
  const float* Wo = (const float*)d_in[7];
  const float* bo = (const float*)d_in[8];
  float* out = (float*)d_out;

  // ws layout: Af[8192*64 f] | Bhi[128*64*8 us] | Blo[same] | S[32 f] | bcat[32 f]
  char* wsb = (char*)d_ws;
  float*          Af   = (float*)wsb;                       // 2 MiB
  unsigned short* BhiS = (unsigned short*)(wsb + (size_t)T_STEPS * 64 * 4);
  unsigned short* BloS = BhiS + (size_t)128 * 64 * 8;       // +128 KiB each
  float*          S    = (float*)(BloS + (size_t)128 * 64 * 8);
  float*          bcat = S + NQQ;

  hipLaunchKernelGGL(prep_kernel, dim3(160), dim3(64), 0, stream,
                     Wf, Wi, Wu, Wo, bf, bi, bu, bo, BhiS, BloS, S, bcat);
  hipLaunchKernelGGL(mfma_gemm_kernel, dim3(T_STEPS / 16), dim3(512), 0, stream,
                     x, (const bf16x8*)BhiS, (const bf16x8*)BloS, bcat, Af);
  hipLaunchKernelGGL(scan_kernel, dim3(NB), dim3(64), 0, stream,
                     (const float4*)Af, S, out);
}